// Round 5
// baseline (3660.549 us; speedup 1.0000x reference)
//
#include <hip/hip_runtime.h>

// ---------------- constants ----------------
#define T_SEQ 2048
#define DMODEL 1024
#define NH 16
#define NKV 4
#define HEAD_DIM 64
#define FFDIM 2816
#define NVOCAB 32000

using u16 = unsigned short;
typedef __bf16 bf16x8 __attribute__((ext_vector_type(8)));
typedef float f32x4 __attribute__((ext_vector_type(4)));

__device__ __forceinline__ float b2f(u16 u) {
    union { unsigned int i; float f; } v; v.i = ((unsigned int)u) << 16; return v.f;
}
__device__ __forceinline__ u16 f2b(float f) {
    unsigned int u = __builtin_bit_cast(unsigned int, f);
    unsigned int r = (u + 0x7FFFu + ((u >> 16) & 1u)) >> 16;
    return (u16)r;
}

// ---------------- embedding gather (f32 table -> f32 x) ----------------
__global__ __launch_bounds__(256) void embed_kernel(const int* __restrict__ toks,
                                                    const float* __restrict__ emb,
                                                    float* __restrict__ x) {
    int idx = blockIdx.x * 256 + threadIdx.x;      // < T_SEQ*DMODEL
    int t = idx >> 10, d = idx & 1023;
    x[idx] = emb[(size_t)toks[t] * DMODEL + d];
}

// ---------------- rmsnorm: f32 in, f32 weight -> bf16 out ----------------
__global__ __launch_bounds__(256) void rmsnorm_kernel(const float* __restrict__ x,
                                                      const float* __restrict__ w,
                                                      u16* __restrict__ out) {
    __shared__ float red[256];
    const int row = blockIdx.x, tid = threadIdx.x;
    const float* xr = x + (size_t)row * DMODEL;
    float vals[4]; float ss = 0.f;
#pragma unroll
    for (int i = 0; i < 4; i++) { float v = xr[tid + 256 * i]; vals[i] = v; ss += v * v; }
    red[tid] = ss; __syncthreads();
    for (int s = 128; s > 0; s >>= 1) { if (tid < s) red[tid] += red[tid + s]; __syncthreads(); }
    float inv = rsqrtf(red[0] * (1.0f / DMODEL) + 1e-5f);
#pragma unroll
    for (int i = 0; i < 4; i++) {
        int c = tid + 256 * i;
        out[(size_t)row * DMODEL + c] = f2b(vals[i] * inv * w[c]);
    }
}

// ---------------- GEMM: C[M,N](f32) = A[M,K](bf16) * B[K,N](bf16 or f32) ----------------
// Block tile 128x128, BK=32, 4 waves (2x2), each wave 64x64 via 4x4 MFMA 16x16x32 frags.
// Bs stores B transposed: Bs[col][k] with k-chunk XOR swizzle for conflict-free reads.
__device__ __forceinline__ int bs_off(int c, int k) {
    return c * 40 + ((((k >> 3) ^ ((c >> 3) & 3)) << 3) | (k & 7));
}

template<bool B_F32>
__global__ __launch_bounds__(256) void gemm_kernel(const u16* __restrict__ A,
                                                   const void* __restrict__ Bv,
                                                   float* __restrict__ C,
                                                   int N, int K) {
    __shared__ __align__(16) u16 As[128 * 40];
    __shared__ __align__(16) u16 Bs[128 * 40];
    const int tid = threadIdx.x;
    const int brow = blockIdx.y, bcol = blockIdx.x;
    const int wid = tid >> 6, lane = tid & 63;
    const int wr = wid >> 1, wc = wid & 1;
    const int lg = lane >> 4, lr = lane & 15;

    f32x4 acc[4][4] = {};

    const int ar = tid >> 2, ac = (tid & 3) << 3;   // A staging: row, col8
    const int bk = tid >> 4, bc = (tid & 15) << 3;  // B staging: k-row, col8

    for (int kb = 0; kb < K; kb += 32) {
        // stage A (128 x 32), two 16B chunks per thread
        {
            const u16* ga = A + (size_t)(brow * 128 + ar) * K + kb + ac;
            *(uint4*)(&As[ar * 40 + ac]) = *(const uint4*)ga;
            *(uint4*)(&As[(ar + 64) * 40 + ac]) = *(const uint4*)(ga + (size_t)64 * K);
        }
        // stage B (32 x 128) -> transposed into Bs[col][k] with swizzle
        if constexpr (B_F32) {
            const float* gb = (const float*)Bv + (size_t)(kb + bk) * N + bcol * 128 + bc;
            float4 a0 = *(const float4*)gb;
            float4 a1 = *(const float4*)(gb + 4);
            float4 b0 = *(const float4*)(gb + (size_t)16 * N);
            float4 b1 = *(const float4*)(gb + (size_t)16 * N + 4);
            float f0[8] = {a0.x, a0.y, a0.z, a0.w, a1.x, a1.y, a1.z, a1.w};
            float f1[8] = {b0.x, b0.y, b0.z, b0.w, b1.x, b1.y, b1.z, b1.w};
#pragma unroll
            for (int i = 0; i < 8; i++) {
                Bs[bs_off(bc + i, bk)] = f2b(f0[i]);
                Bs[bs_off(bc + i, bk + 16)] = f2b(f1[i]);
            }
        } else {
            const u16* gb = (const u16*)Bv + (size_t)(kb + bk) * N + bcol * 128 + bc;
            uint4 v0 = *(const uint4*)gb;
            uint4 v1 = *(const uint4*)(gb + (size_t)16 * N);
            const u16* p0 = (const u16*)&v0;
            const u16* p1 = (const u16*)&v1;
#pragma unroll
            for (int i = 0; i < 8; i++) {
                Bs[bs_off(bc + i, bk)] = p0[i];
                Bs[bs_off(bc + i, bk + 16)] = p1[i];
            }
        }
        __syncthreads();

        bf16x8 aF[4], bF[4];
#pragma unroll
        for (int m = 0; m < 4; m++)
            aF[m] = *(const bf16x8*)(&As[(wr * 64 + m * 16 + lr) * 40 + lg * 8]);
#pragma unroll
        for (int n = 0; n < 4; n++) {
            int c = wc * 64 + n * 16 + lr;
            bF[n] = *(const bf16x8*)(&Bs[c * 40 + ((lg ^ ((c >> 3) & 3)) << 3)]);
        }
#pragma unroll
        for (int m = 0; m < 4; m++)
#pragma unroll
            for (int n = 0; n < 4; n++)
                acc[m][n] = __builtin_amdgcn_mfma_f32_16x16x32_bf16(aF[m], bF[n], acc[m][n], 0, 0, 0);
        __syncthreads();
    }

#pragma unroll
    for (int m = 0; m < 4; m++) {
#pragma unroll
        for (int n = 0; n < 4; n++) {
#pragma unroll
            for (int j = 0; j < 4; j++) {
                int row = brow * 128 + wr * 64 + m * 16 + lg * 4 + j;
                int col = bcol * 128 + wc * 64 + n * 16 + lr;
                C[(size_t)row * N + col] = acc[m][n][j];
            }
        }
    }
}

// ---------------- RoPE (f32 in -> bf16 out), interleaved pairs ----------------
__global__ __launch_bounds__(256) void rope_kernel(const float* __restrict__ in,
                                                   u16* __restrict__ out, int heads) {
    int idx = blockIdx.x * 256 + threadIdx.x;
    int total = T_SEQ * heads * 32;
    if (idx >= total) return;
    int i = idx & 31;          // pair index within head dim
    int rest = idx >> 5;       // t*heads + h
    int t = rest / heads;
    float inv = expf(-(float)i * (9.210340371976184f / 32.0f));  // theta^{-2i/64}
    float ang = (float)t * inv;
    float c = cosf(ang), s = sinf(ang);
    size_t base = (size_t)rest * HEAD_DIM + 2 * i;
    float x0 = in[base], x1 = in[base + 1];
    out[base]     = f2b(x0 * c - x1 * s);
    out[base + 1] = f2b(x0 * s + x1 * c);
}

// ---------------- f32 -> bf16 cast ----------------
__global__ __launch_bounds__(256) void cast_kernel(const float* __restrict__ in,
                                                   u16* __restrict__ out, int n) {
    int i = blockIdx.x * 256 + threadIdx.x;
    if (i < n) out[i] = f2b(in[i]);
}

// ---------------- attention: one block per (t, head), bf16 q/k/v ----------------
__global__ __launch_bounds__(256) void attn_kernel(const u16* __restrict__ q,
                                                   const u16* __restrict__ k,
                                                   const u16* __restrict__ v,
                                                   u16* __restrict__ out) {
    __shared__ float sc[T_SEQ];
    __shared__ float qv[HEAD_DIM];
    __shared__ float red[256];
    __shared__ float ob[4][HEAD_DIM];
    const int t = blockIdx.x, h = blockIdx.y, kvh = h >> 2;
    const int tid = threadIdx.x;

    if (tid < HEAD_DIM) qv[tid] = b2f(q[((size_t)t * NH + h) * HEAD_DIM + tid]);
    __syncthreads();

    // phase 1: scores + max
    float lmax = -1e30f;
    for (int p = tid; p <= t; p += 256) {
        const u16* kr = k + ((size_t)p * NKV + kvh) * HEAD_DIM;
        float dot = 0.f;
#pragma unroll
        for (int d0 = 0; d0 < HEAD_DIM; d0 += 8) {
            uint4 kv8 = *(const uint4*)(kr + d0);
            const u16* ks = (const u16*)&kv8;
#pragma unroll
            for (int i = 0; i < 8; i++) dot += qv[d0 + i] * b2f(ks[i]);
        }
        dot *= 0.125f;
        sc[p] = dot;
        lmax = fmaxf(lmax, dot);
    }
    red[tid] = lmax; __syncthreads();
    for (int s = 128; s > 0; s >>= 1) { if (tid < s) red[tid] = fmaxf(red[tid], red[tid + s]); __syncthreads(); }
    float mx = red[0]; __syncthreads();

    // phase 2: exp + sum
    float lsum = 0.f;
    for (int p = tid; p <= t; p += 256) { float e = __expf(sc[p] - mx); sc[p] = e; lsum += e; }
    red[tid] = lsum; __syncthreads();
    for (int s = 128; s > 0; s >>= 1) { if (tid < s) red[tid] += red[tid + s]; __syncthreads(); }
    float inv = 1.0f / red[0];

    // phase 3: output = sum_p prob[p] * v[p][:]
    const int d = tid & 63, ch = tid >> 6;
    float acc = 0.f;
    for (int p = ch; p <= t; p += 4)
        acc += sc[p] * b2f(v[((size_t)p * NKV + kvh) * HEAD_DIM + d]);
    ob[ch][d] = acc; __syncthreads();
    if (tid < HEAD_DIM) {
        float o = (ob[0][tid] + ob[1][tid] + ob[2][tid] + ob[3][tid]) * inv;
        out[((size_t)t * NH + h) * HEAD_DIM + tid] = f2b(o);
    }
}

// ---------------- silu(gate) * up -> bf16 ----------------
__global__ __launch_bounds__(256) void silu_mul_kernel(const float* __restrict__ g,
                                                       const float* __restrict__ u,
                                                       u16* __restrict__ out, int n) {
    int i = blockIdx.x * 256 + threadIdx.x;
    if (i < n) {
        float gv = g[i];
        float s = gv / (1.f + __expf(-gv));
        out[i] = f2b(s * u[i]);
    }
}

// ---------------- residual add: x += y ----------------
__global__ __launch_bounds__(256) void add_kernel(float* __restrict__ x,
                                                  const float* __restrict__ y, int n) {
    int i = blockIdx.x * 256 + threadIdx.x;
    if (i < n) x[i] += y[i];
}

// ---------------- host launch ----------------
extern "C" void kernel_launch(void* const* d_in, const int* in_sizes, int n_in,
                              void* d_out, int out_size, void* d_ws, size_t ws_size,
                              hipStream_t stream) {
    const int*   toks = (const int*)d_in[0];
    const float* emb  = (const float*)d_in[1];
    const float* Wq   = (const float*)d_in[2];
    const float* Wk   = (const float*)d_in[3];
    const float* Wv   = (const float*)d_in[4];
    const float* Wo   = (const float*)d_in[5];
    const float* Wg   = (const float*)d_in[6];
    const float* Wu   = (const float*)d_in[7];
    const float* Wd   = (const float*)d_in[8];
    const float* ln1  = (const float*)d_in[9];
    const float* ln2  = (const float*)d_in[10];
    const float* nw   = (const float*)d_in[11];
    const float* Wlm  = (const float*)d_in[12];

    // ---- scratch layout ----
    // d_out is f32 [2048, 32000] = 262 MB. All scratch below lives in d_out and is
    // DEAD before the LM-head GEMM overwrites the full output. `h` (LM GEMM input)
    // and optional bf16 Wlm copy live in d_ws to avoid aliasing.
    char* ob = (char*)d_out;
    const size_t MB = 1024 * 1024;
    float* x   = (float*)(ob + 0 * MB);    // 8MB   f32 residual stream [T,D]
    float* fA  = (float*)(ob + 8 * MB);    // 23.1MB f32 scratch [T,FFDIM]
    float* fB  = (float*)(ob + 32 * MB);   // 23.1MB f32 scratch [T,FFDIM]
    float* fC  = (float*)(ob + 56 * MB);   // 2MB   f32 scratch [T,KVH*HD]
    u16* qb    = (u16*)  (ob + 58 * MB);   // 4MB
    u16* kb    = (u16*)  (ob + 62 * MB);   // 1MB
    u16* vb    = (u16*)  (ob + 63 * MB);   // 1MB
    u16* attnb = (u16*)  (ob + 64 * MB);   // 4MB
    u16* ffb   = (u16*)  (ob + 68 * MB);   // 11.5MB
    u16* h     = (u16*)  d_ws;             // 4MB   bf16 [T,D]
    bool ws_big = ws_size >= 72 * MB;
    u16* wlmb  = ws_big ? (u16*)((char*)d_ws + 4 * MB) : nullptr;  // 62.5MB bf16 Wlm
    (void)in_sizes; (void)n_in; (void)out_size;

    dim3 blk(256);
    auto gemm_f32w = [&](const u16* A, const float* B, float* C, int N, int K) {
        dim3 g(N / 128, T_SEQ / 128);
        gemm_kernel<true><<<g, blk, 0, stream>>>(A, (const void*)B, C, N, K);
    };

    // embedding
    embed_kernel<<<dim3(T_SEQ * DMODEL / 256), blk, 0, stream>>>(toks, emb, x);

    for (int l = 0; l < 2; l++) {
        const float* wq = Wq + (size_t)l * DMODEL * (NH * HEAD_DIM);
        const float* wk = Wk + (size_t)l * DMODEL * (NKV * HEAD_DIM);
        const float* wv = Wv + (size_t)l * DMODEL * (NKV * HEAD_DIM);
        const float* wo = Wo + (size_t)l * (NH * HEAD_DIM) * DMODEL;
        const float* wg = Wg + (size_t)l * DMODEL * FFDIM;
        const float* wu = Wu + (size_t)l * DMODEL * FFDIM;
        const float* wd = Wd + (size_t)l * FFDIM * DMODEL;

        // attn block
        rmsnorm_kernel<<<dim3(T_SEQ), blk, 0, stream>>>(x, ln1 + (size_t)l * DMODEL, h);
        gemm_f32w(h, wq, fA, NH * HEAD_DIM, DMODEL);   // q
        gemm_f32w(h, wk, fB, NKV * HEAD_DIM, DMODEL);  // k
        gemm_f32w(h, wv, fC, NKV * HEAD_DIM, DMODEL);  // v
        rope_kernel<<<dim3(T_SEQ * NH * 32 / 256), blk, 0, stream>>>(fA, qb, NH);
        rope_kernel<<<dim3(T_SEQ * NKV * 32 / 256), blk, 0, stream>>>(fB, kb, NKV);
        cast_kernel<<<dim3(T_SEQ * NKV * HEAD_DIM / 256), blk, 0, stream>>>(fC, vb, T_SEQ * NKV * HEAD_DIM);
        attn_kernel<<<dim3(T_SEQ, NH), blk, 0, stream>>>(qb, kb, vb, attnb);
        gemm_f32w(attnb, wo, fA, DMODEL, NH * HEAD_DIM);
        add_kernel<<<dim3(T_SEQ * DMODEL / 256), blk, 0, stream>>>(x, fA, T_SEQ * DMODEL);

        // ffn block
        rmsnorm_kernel<<<dim3(T_SEQ), blk, 0, stream>>>(x, ln2 + (size_t)l * DMODEL, h);
        gemm_f32w(h, wg, fA, FFDIM, DMODEL);
        gemm_f32w(h, wu, fB, FFDIM, DMODEL);
        silu_mul_kernel<<<dim3(T_SEQ * FFDIM / 256), blk, 0, stream>>>(fA, fB, ffb, T_SEQ * FFDIM);
        gemm_f32w(ffb, wd, fA, DMODEL, FFDIM);
        add_kernel<<<dim3(T_SEQ * DMODEL / 256), blk, 0, stream>>>(x, fA, T_SEQ * DMODEL);
    }

    // final norm + lm head (reads h/wlmb from d_ws, overwrites all of d_out with f32)
    rmsnorm_kernel<<<dim3(T_SEQ), blk, 0, stream>>>(x, nw, h);
    {
        dim3 g(NVOCAB / 128, T_SEQ / 128);
        if (wlmb) {
            cast_kernel<<<dim3(DMODEL * NVOCAB / 256), blk, 0, stream>>>(Wlm, wlmb, DMODEL * NVOCAB);
            gemm_kernel<false><<<g, blk, 0, stream>>>(h, (const void*)wlmb, (float*)d_out, NVOCAB, DMODEL);
        } else {
            gemm_kernel<true><<<g, blk, 0, stream>>>(h, (const void*)Wlm, (float*)d_out, NVOCAB, DMODEL);
        }
    }
}

// Round 6
// 1312.570 us; speedup vs baseline: 2.7888x; 2.7888x over previous
//
#include <hip/hip_runtime.h>

// ---------------- constants ----------------
#define T_SEQ 2048
#define DMODEL 1024
#define NH 16
#define NKV 4
#define HEAD_DIM 64
#define FFDIM 2816
#define NVOCAB 32000

// flash-attn tile params
#define QBLK 64
#define KBLK 128
#define KSS 72    // Ks row stride (u16): 64 d + 8 pad, 16B-aligned, GEMM-proven bank spread
#define VTS 136   // Vt row stride (u16): 128 keys + 8 pad
#define PSS 136   // Ps row stride (u16): 128 keys + 8 pad

using u16 = unsigned short;
typedef __bf16 bf16x8 __attribute__((ext_vector_type(8)));
typedef float f32x4 __attribute__((ext_vector_type(4)));

__device__ __forceinline__ float b2f(u16 u) {
    union { unsigned int i; float f; } v; v.i = ((unsigned int)u) << 16; return v.f;
}
__device__ __forceinline__ u16 f2b(float f) {
    unsigned int u = __builtin_bit_cast(unsigned int, f);
    unsigned int r = (u + 0x7FFFu + ((u >> 16) & 1u)) >> 16;
    return (u16)r;
}

// ---------------- embedding gather (f32 table -> f32 x) ----------------
__global__ __launch_bounds__(256) void embed_kernel(const int* __restrict__ toks,
                                                    const float* __restrict__ emb,
                                                    float* __restrict__ x) {
    int idx = blockIdx.x * 256 + threadIdx.x;      // < T_SEQ*DMODEL
    int t = idx >> 10, d = idx & 1023;
    x[idx] = emb[(size_t)toks[t] * DMODEL + d];
}

// ---------------- rmsnorm: f32 in, f32 weight -> bf16 out ----------------
__global__ __launch_bounds__(256) void rmsnorm_kernel(const float* __restrict__ x,
                                                      const float* __restrict__ w,
                                                      u16* __restrict__ out) {
    __shared__ float red[256];
    const int row = blockIdx.x, tid = threadIdx.x;
    const float* xr = x + (size_t)row * DMODEL;
    float vals[4]; float ss = 0.f;
#pragma unroll
    for (int i = 0; i < 4; i++) { float v = xr[tid + 256 * i]; vals[i] = v; ss += v * v; }
    red[tid] = ss; __syncthreads();
    for (int s = 128; s > 0; s >>= 1) { if (tid < s) red[tid] += red[tid + s]; __syncthreads(); }
    float inv = rsqrtf(red[0] * (1.0f / DMODEL) + 1e-5f);
#pragma unroll
    for (int i = 0; i < 4; i++) {
        int c = tid + 256 * i;
        out[(size_t)row * DMODEL + c] = f2b(vals[i] * inv * w[c]);
    }
}

// ---------------- GEMM: C[M,N] = A[M,K](bf16) * B[K,N](bf16 or f32) ----------------
// Block tile 128x128, BK=32, 4 waves (2x2), each wave 64x64 via 4x4 MFMA 16x16x32 frags.
// OUT_VT: write bf16 transposed C^T[col][row] (used for V so attention gets V^T directly).
__device__ __forceinline__ int bs_off(int c, int k) {
    return c * 40 + ((((k >> 3) ^ ((c >> 3) & 3)) << 3) | (k & 7));
}

template<bool B_F32, bool OUT_VT>
__global__ __launch_bounds__(256) void gemm_kernel(const u16* __restrict__ A,
                                                   const void* __restrict__ Bv,
                                                   void* __restrict__ Cp,
                                                   int N, int K) {
    __shared__ __align__(16) u16 As[128 * 40];
    __shared__ __align__(16) u16 Bs[128 * 40];
    const int tid = threadIdx.x;
    const int brow = blockIdx.y, bcol = blockIdx.x;
    const int wid = tid >> 6, lane = tid & 63;
    const int wr = wid >> 1, wc = wid & 1;
    const int lg = lane >> 4, lr = lane & 15;

    f32x4 acc[4][4] = {};

    const int ar = tid >> 2, ac = (tid & 3) << 3;   // A staging: row, col8
    const int bk = tid >> 4, bc = (tid & 15) << 3;  // B staging: k-row, col8

    for (int kb = 0; kb < K; kb += 32) {
        {
            const u16* ga = A + (size_t)(brow * 128 + ar) * K + kb + ac;
            *(uint4*)(&As[ar * 40 + ac]) = *(const uint4*)ga;
            *(uint4*)(&As[(ar + 64) * 40 + ac]) = *(const uint4*)(ga + (size_t)64 * K);
        }
        if constexpr (B_F32) {
            const float* gb = (const float*)Bv + (size_t)(kb + bk) * N + bcol * 128 + bc;
            float4 a0 = *(const float4*)gb;
            float4 a1 = *(const float4*)(gb + 4);
            float4 b0 = *(const float4*)(gb + (size_t)16 * N);
            float4 b1 = *(const float4*)(gb + (size_t)16 * N + 4);
            float f0[8] = {a0.x, a0.y, a0.z, a0.w, a1.x, a1.y, a1.z, a1.w};
            float f1[8] = {b0.x, b0.y, b0.z, b0.w, b1.x, b1.y, b1.z, b1.w};
#pragma unroll
            for (int i = 0; i < 8; i++) {
                Bs[bs_off(bc + i, bk)] = f2b(f0[i]);
                Bs[bs_off(bc + i, bk + 16)] = f2b(f1[i]);
            }
        } else {
            const u16* gb = (const u16*)Bv + (size_t)(kb + bk) * N + bcol * 128 + bc;
            uint4 v0 = *(const uint4*)gb;
            uint4 v1 = *(const uint4*)(gb + (size_t)16 * N);
            const u16* p0 = (const u16*)&v0;
            const u16* p1 = (const u16*)&v1;
#pragma unroll
            for (int i = 0; i < 8; i++) {
                Bs[bs_off(bc + i, bk)] = p0[i];
                Bs[bs_off(bc + i, bk + 16)] = p1[i];
            }
        }
        __syncthreads();

        bf16x8 aF[4], bF[4];
#pragma unroll
        for (int m = 0; m < 4; m++)
            aF[m] = *(const bf16x8*)(&As[(wr * 64 + m * 16 + lr) * 40 + lg * 8]);
#pragma unroll
        for (int n = 0; n < 4; n++) {
            int c = wc * 64 + n * 16 + lr;
            bF[n] = *(const bf16x8*)(&Bs[c * 40 + ((lg ^ ((c >> 3) & 3)) << 3)]);
        }
#pragma unroll
        for (int m = 0; m < 4; m++)
#pragma unroll
            for (int n = 0; n < 4; n++)
                acc[m][n] = __builtin_amdgcn_mfma_f32_16x16x32_bf16(aF[m], bF[n], acc[m][n], 0, 0, 0);
        __syncthreads();
    }

#pragma unroll
    for (int m = 0; m < 4; m++) {
#pragma unroll
        for (int n = 0; n < 4; n++) {
            if constexpr (OUT_VT) {
                int col = bcol * 128 + wc * 64 + n * 16 + lr;
                int row0 = brow * 128 + wr * 64 + m * 16 + lg * 4;
                union { u16 s[4]; unsigned long long q; } pk;
#pragma unroll
                for (int j = 0; j < 4; j++) pk.s[j] = f2b(acc[m][n][j]);
                *(unsigned long long*)(&((u16*)Cp)[(size_t)col * T_SEQ + row0]) = pk.q;
            } else {
#pragma unroll
                for (int j = 0; j < 4; j++) {
                    int row = brow * 128 + wr * 64 + m * 16 + lg * 4 + j;
                    int col = bcol * 128 + wc * 64 + n * 16 + lr;
                    ((float*)Cp)[(size_t)row * N + col] = acc[m][n][j];
                }
            }
        }
    }
}

// ---------------- RoPE (f32 in -> bf16 out), interleaved pairs ----------------
__global__ __launch_bounds__(256) void rope_kernel(const float* __restrict__ in,
                                                   u16* __restrict__ out, int heads) {
    int idx = blockIdx.x * 256 + threadIdx.x;
    int total = T_SEQ * heads * 32;
    if (idx >= total) return;
    int i = idx & 31;
    int rest = idx >> 5;       // t*heads + h
    int t = rest / heads;
    float inv = expf(-(float)i * (9.210340371976184f / 32.0f));
    float ang = (float)t * inv;
    float c = cosf(ang), s = sinf(ang);
    size_t base = (size_t)rest * HEAD_DIM + 2 * i;
    float x0 = in[base], x1 = in[base + 1];
    out[base]     = f2b(x0 * c - x1 * s);
    out[base + 1] = f2b(x0 * s + x1 * c);
}

// ---------------- f32 -> bf16 cast ----------------
__global__ __launch_bounds__(256) void cast_kernel(const float* __restrict__ in,
                                                   u16* __restrict__ out, int n) {
    int i = blockIdx.x * 256 + threadIdx.x;
    if (i < n) out[i] = f2b(in[i]);
}

// ---------------- flash attention: block = 64 queries x 1 head ----------------
// q: [t][NH][64] bf16 (rope'd), k: [t][NKV][64] bf16 (rope'd), vt: [NKV*64][T] bf16.
// 4 waves, wave w owns q rows qb0+16w..+15. Online softmax in C-registers, P via
// wave-private LDS rows, PV with MFMA. Fragment layouts match the verified GEMM.
__global__ __launch_bounds__(256) void fattn_kernel(const u16* __restrict__ q,
                                                    const u16* __restrict__ k,
                                                    const u16* __restrict__ vt,
                                                    u16* __restrict__ out) {
    __shared__ __align__(16) u16 Ks[KBLK * KSS];
    __shared__ __align__(16) u16 Vt[HEAD_DIM * VTS];
    __shared__ __align__(16) u16 Ps[QBLK * PSS];
    const int tid = threadIdx.x;
    const int qb0 = blockIdx.x * QBLK, h = blockIdx.y, kvh = h >> 2;
    const int w = tid >> 6, lane = tid & 63;
    const int lg = lane >> 4, lr = lane & 15;

    // Q fragments (A-layout): row = lr, k = lg*8+j within each 32-slice of d
    bf16x8 qf0, qf1;
    {
        const u16* src = q + ((size_t)(qb0 + w * 16 + lr) * NH + h) * HEAD_DIM;
        qf0 = *(const bf16x8*)(src + lg * 8);
        qf1 = *(const bf16x8*)(src + 32 + lg * 8);
    }

    f32x4 acc_o[4] = {};
    float m_run[4] = {-1e30f, -1e30f, -1e30f, -1e30f};
    float l_run[4] = {0.f, 0.f, 0.f, 0.f};

    const int ntiles = (qb0 + QBLK - 1) / KBLK + 1;

    for (int kt = 0; kt < ntiles; kt++) {
        const int kb = kt * KBLK;
        __syncthreads();
        // stage K tile [128 keys][64 d] row-major
        for (int c = tid; c < KBLK * 8; c += 256) {
            int row = c >> 3, c8 = (c & 7) << 3;
            *(uint4*)(&Ks[row * KSS + c8]) =
                *(const uint4*)(k + ((size_t)(kb + row) * NKV + kvh) * HEAD_DIM + c8);
        }
        // stage V^T tile [64 d][128 keys] from globally-transposed vt
        for (int c = tid; c < HEAD_DIM * 16; c += 256) {
            int d = c >> 4, c16 = (c & 15) << 3;
            *(uint4*)(&Vt[d * VTS + c16]) =
                *(const uint4*)(vt + (size_t)(kvh * HEAD_DIM + d) * T_SEQ + kb + c16);
        }
        __syncthreads();

        // S = Q K^T : 8 n-frags of 16 keys, K-dim = 64 in two 32-slices
        f32x4 s[8] = {};
#pragma unroll
        for (int n = 0; n < 8; n++) {
            bf16x8 kf0 = *(const bf16x8*)(&Ks[(n * 16 + lr) * KSS + lg * 8]);
            bf16x8 kf1 = *(const bf16x8*)(&Ks[(n * 16 + lr) * KSS + 32 + lg * 8]);
            s[n] = __builtin_amdgcn_mfma_f32_16x16x32_bf16(qf0, kf0, s[n], 0, 0, 0);
            s[n] = __builtin_amdgcn_mfma_f32_16x16x32_bf16(qf1, kf1, s[n], 0, 0, 0);
        }

        // online softmax per row j (C-layout: row q = 4*lg+j, col key = n*16+lr)
#pragma unroll
        for (int j = 0; j < 4; j++) {
            int q_g = qb0 + w * 16 + lg * 4 + j;
            float sv[8];
            float tmax = -1e30f;
#pragma unroll
            for (int n = 0; n < 8; n++) {
                float xx = s[n][j] * 0.125f;
                if (kb + n * 16 + lr > q_g) xx = -1e30f;
                sv[n] = xx;
                tmax = fmaxf(tmax, xx);
            }
#pragma unroll
            for (int mm = 1; mm < 16; mm <<= 1) tmax = fmaxf(tmax, __shfl_xor(tmax, mm));
            float mn = fmaxf(m_run[j], tmax);
            float sc = __expf(m_run[j] - mn);
            m_run[j] = mn;
            float rsum = 0.f;
#pragma unroll
            for (int n = 0; n < 8; n++) {
                float p = __expf(sv[n] - mn);
                rsum += p;
                Ps[(w * 16 + lg * 4 + j) * PSS + n * 16 + lr] = f2b(p);
            }
#pragma unroll
            for (int mm = 1; mm < 16; mm <<= 1) rsum += __shfl_xor(rsum, mm);
            l_run[j] = l_run[j] * sc + rsum;
#pragma unroll
            for (int n = 0; n < 4; n++) acc_o[n][j] *= sc;
        }

        // PV: O[16 q][64 d] += P[16 q][128 k] * V[128 k][64 d]
#pragma unroll
        for (int ks = 0; ks < 4; ks++) {
            bf16x8 pf = *(const bf16x8*)(&Ps[(w * 16 + lr) * PSS + ks * 32 + lg * 8]);
#pragma unroll
            for (int n = 0; n < 4; n++) {
                bf16x8 vf = *(const bf16x8*)(&Vt[(n * 16 + lr) * VTS + ks * 32 + lg * 8]);
                acc_o[n] = __builtin_amdgcn_mfma_f32_16x16x32_bf16(pf, vf, acc_o[n], 0, 0, 0);
            }
        }
    }

    // write O / l  -> out[t][h][d] bf16
#pragma unroll
    for (int n = 0; n < 4; n++) {
#pragma unroll
        for (int j = 0; j < 4; j++) {
            int t = qb0 + w * 16 + lg * 4 + j;
            int d = n * 16 + lr;
            out[((size_t)t * NH + h) * HEAD_DIM + d] = f2b(acc_o[n][j] / l_run[j]);
        }
    }
}

// ---------------- silu(gate) * up -> bf16 ----------------
__global__ __launch_bounds__(256) void silu_mul_kernel(const float* __restrict__ g,
                                                       const float* __restrict__ u,
                                                       u16* __restrict__ out, int n) {
    int i = blockIdx.x * 256 + threadIdx.x;
    if (i < n) {
        float gv = g[i];
        float s = gv / (1.f + __expf(-gv));
        out[i] = f2b(s * u[i]);
    }
}

// ---------------- residual add: x += y ----------------
__global__ __launch_bounds__(256) void add_kernel(float* __restrict__ x,
                                                  const float* __restrict__ y, int n) {
    int i = blockIdx.x * 256 + threadIdx.x;
    if (i < n) x[i] += y[i];
}

// ---------------- host launch ----------------
extern "C" void kernel_launch(void* const* d_in, const int* in_sizes, int n_in,
                              void* d_out, int out_size, void* d_ws, size_t ws_size,
                              hipStream_t stream) {
    const int*   toks = (const int*)d_in[0];
    const float* emb  = (const float*)d_in[1];
    const float* Wq   = (const float*)d_in[2];
    const float* Wk   = (const float*)d_in[3];
    const float* Wv   = (const float*)d_in[4];
    const float* Wo   = (const float*)d_in[5];
    const float* Wg   = (const float*)d_in[6];
    const float* Wu   = (const float*)d_in[7];
    const float* Wd   = (const float*)d_in[8];
    const float* ln1  = (const float*)d_in[9];
    const float* ln2  = (const float*)d_in[10];
    const float* nw   = (const float*)d_in[11];
    const float* Wlm  = (const float*)d_in[12];

    // ---- scratch layout ----
    // d_out is f32 [2048, 32000] = 262 MB. Scratch below is DEAD before the LM-head
    // GEMM overwrites d_out. `h` and optional bf16 Wlm live in d_ws (no aliasing).
    char* ob = (char*)d_out;
    const size_t MB = 1024 * 1024;
    float* x   = (float*)(ob + 0 * MB);    // 8MB    f32 residual [T,D]
    float* fA  = (float*)(ob + 8 * MB);    // 23.1MB f32 scratch [T,FFDIM]
    float* fB  = (float*)(ob + 32 * MB);   // 23.1MB f32 scratch [T,FFDIM]
    u16* vt    = (u16*)  (ob + 56 * MB);   // 1MB    bf16 V^T [NKV*64][T]
    u16* qb    = (u16*)  (ob + 58 * MB);   // 4MB    bf16 q rope'd
    u16* kb    = (u16*)  (ob + 62 * MB);   // 1MB    bf16 k rope'd
    u16* attnb = (u16*)  (ob + 64 * MB);   // 4MB    bf16 attn out
    u16* ffb   = (u16*)  (ob + 68 * MB);   // 11.5MB bf16 silu*up
    u16* h     = (u16*)  d_ws;             // 4MB    bf16 [T,D]
    bool ws_big = ws_size >= 72 * MB;
    u16* wlmb  = ws_big ? (u16*)((char*)d_ws + 4 * MB) : nullptr;  // 62.5MB bf16 Wlm
    (void)in_sizes; (void)n_in; (void)out_size;

    dim3 blk(256);
    auto gemm_f32w = [&](const u16* A, const float* B, float* C, int N, int K) {
        dim3 g(N / 128, T_SEQ / 128);
        gemm_kernel<true, false><<<g, blk, 0, stream>>>(A, (const void*)B, (void*)C, N, K);
    };

    embed_kernel<<<dim3(T_SEQ * DMODEL / 256), blk, 0, stream>>>(toks, emb, x);

    for (int l = 0; l < 2; l++) {
        const float* wq = Wq + (size_t)l * DMODEL * (NH * HEAD_DIM);
        const float* wk = Wk + (size_t)l * DMODEL * (NKV * HEAD_DIM);
        const float* wv = Wv + (size_t)l * DMODEL * (NKV * HEAD_DIM);
        const float* wo = Wo + (size_t)l * (NH * HEAD_DIM) * DMODEL;
        const float* wg = Wg + (size_t)l * DMODEL * FFDIM;
        const float* wu = Wu + (size_t)l * DMODEL * FFDIM;
        const float* wd = Wd + (size_t)l * FFDIM * DMODEL;

        // attn block
        rmsnorm_kernel<<<dim3(T_SEQ), blk, 0, stream>>>(x, ln1 + (size_t)l * DMODEL, h);
        gemm_f32w(h, wq, fA, NH * HEAD_DIM, DMODEL);   // q -> fA (f32)
        gemm_f32w(h, wk, fB, NKV * HEAD_DIM, DMODEL);  // k -> fB (f32)
        {   // v -> vt (bf16, transposed)
            dim3 g((NKV * HEAD_DIM) / 128, T_SEQ / 128);
            gemm_kernel<true, true><<<g, blk, 0, stream>>>(h, (const void*)wv, (void*)vt,
                                                           NKV * HEAD_DIM, DMODEL);
        }
        rope_kernel<<<dim3(T_SEQ * NH * 32 / 256), blk, 0, stream>>>(fA, qb, NH);
        rope_kernel<<<dim3(T_SEQ * NKV * 32 / 256), blk, 0, stream>>>(fB, kb, NKV);
        fattn_kernel<<<dim3(T_SEQ / QBLK, NH), blk, 0, stream>>>(qb, kb, vt, attnb);
        gemm_f32w(attnb, wo, fA, DMODEL, NH * HEAD_DIM);
        add_kernel<<<dim3(T_SEQ * DMODEL / 256), blk, 0, stream>>>(x, fA, T_SEQ * DMODEL);

        // ffn block
        rmsnorm_kernel<<<dim3(T_SEQ), blk, 0, stream>>>(x, ln2 + (size_t)l * DMODEL, h);
        gemm_f32w(h, wg, fA, FFDIM, DMODEL);
        gemm_f32w(h, wu, fB, FFDIM, DMODEL);
        silu_mul_kernel<<<dim3(T_SEQ * FFDIM / 256), blk, 0, stream>>>(fA, fB, ffb, T_SEQ * FFDIM);
        gemm_f32w(ffb, wd, fA, DMODEL, FFDIM);
        add_kernel<<<dim3(T_SEQ * DMODEL / 256), blk, 0, stream>>>(x, fA, T_SEQ * DMODEL);
    }

    // final norm + lm head
    rmsnorm_kernel<<<dim3(T_SEQ), blk, 0, stream>>>(x, nw, h);
    {
        dim3 g(NVOCAB / 128, T_SEQ / 128);
        if (wlmb) {
            cast_kernel<<<dim3(DMODEL * NVOCAB / 256), blk, 0, stream>>>(Wlm, wlmb, DMODEL * NVOCAB);
            gemm_kernel<false, false><<<g, blk, 0, stream>>>(h, (const void*)wlmb, d_out, NVOCAB, DMODEL);
        } else {
            gemm_kernel<true, false><<<g, blk, 0, stream>>>(h, (const void*)Wlm, d_out, NVOCAB, DMODEL);
        }
    }
}

// Round 7
// 1086.140 us; speedup vs baseline: 3.3702x; 1.2085x over previous
//
#include <hip/hip_runtime.h>

// ---------------- constants ----------------
#define T_SEQ 2048
#define DMODEL 1024
#define NH 16
#define NKV 4
#define HEAD_DIM 64
#define FFDIM 2816
#define NVOCAB 32000

// flash-attn tile params
#define QBLK 64
#define KBLK 128
#define KSS 72
#define VTS 136
#define PSS 136

using u16 = unsigned short;
typedef __bf16 bf16x8 __attribute__((ext_vector_type(8)));
typedef float f32x4 __attribute__((ext_vector_type(4)));

__device__ __forceinline__ float b2f(u16 u) {
    union { unsigned int i; float f; } v; v.i = ((unsigned int)u) << 16; return v.f;
}
__device__ __forceinline__ u16 f2b(float f) {
    unsigned int u = __builtin_bit_cast(unsigned int, f);
    unsigned int r = (u + 0x7FFFu + ((u >> 16) & 1u)) >> 16;
    return (u16)r;
}

// ---------------- embedding gather ----------------
__global__ __launch_bounds__(256) void embed_kernel(const int* __restrict__ toks,
                                                    const float* __restrict__ emb,
                                                    float* __restrict__ x) {
    int idx = blockIdx.x * 256 + threadIdx.x;
    int t = idx >> 10, d = idx & 1023;
    x[idx] = emb[(size_t)toks[t] * DMODEL + d];
}

// ---------------- rmsnorm: f32 in -> bf16 out ----------------
__global__ __launch_bounds__(256) void rmsnorm_kernel(const float* __restrict__ x,
                                                      const float* __restrict__ w,
                                                      u16* __restrict__ out) {
    __shared__ float red[256];
    const int row = blockIdx.x, tid = threadIdx.x;
    const float* xr = x + (size_t)row * DMODEL;
    float vals[4]; float ss = 0.f;
#pragma unroll
    for (int i = 0; i < 4; i++) { float v = xr[tid + 256 * i]; vals[i] = v; ss += v * v; }
    red[tid] = ss; __syncthreads();
    for (int s = 128; s > 0; s >>= 1) { if (tid < s) red[tid] += red[tid + s]; __syncthreads(); }
    float inv = rsqrtf(red[0] * (1.0f / DMODEL) + 1e-5f);
#pragma unroll
    for (int i = 0; i < 4; i++) {
        int c = tid + 256 * i;
        out[(size_t)row * DMODEL + c] = f2b(vals[i] * inv * w[c]);
    }
}

// ---------------- transpose-cast: in[K][N] f32 -> out[N][K] bf16 ----------------
__global__ __launch_bounds__(256) void tcast_kernel(const float* __restrict__ in,
                                                    u16* __restrict__ out, int K, int N) {
    __shared__ float tile[32][33];
    int bx = blockIdx.x * 32;  // N
    int by = blockIdx.y * 32;  // K
    int tx = threadIdx.x & 31, ty = threadIdx.x >> 5;
#pragma unroll
    for (int i = 0; i < 32; i += 8)
        tile[ty + i][tx] = in[(size_t)(by + ty + i) * N + bx + tx];
    __syncthreads();
#pragma unroll
    for (int i = 0; i < 32; i += 8)
        out[(size_t)(bx + ty + i) * K + by + tx] = f2b(tile[tx][ty + i]);
}

// ---------------- GEMM-BT: C[M,N] = A[M,K](bf16) * BT[N,K](bf16) ----------------
// Tile 128x128, BK=32, 4 waves (2x2). Both A and BT staged identically (the
// proven As pattern): coalesced uint4 loads -> b128 writes into padded [128][40].
// OUT_VT: write bf16 transposed C^T[col][row] (V for attention).
// Grid: x = M-tiles (fast) so 16 consecutive blocks share one BT panel (L2 reuse).
template<bool OUT_VT>
__global__ __launch_bounds__(256) void gemm_bt_kernel(const u16* __restrict__ A,
                                                      const u16* __restrict__ BT,
                                                      void* __restrict__ Cp,
                                                      int N, int K) {
    __shared__ __align__(16) u16 As[128 * 40];
    __shared__ __align__(16) u16 Bs[128 * 40];
    const int tid = threadIdx.x;
    const int brow = blockIdx.x, bcol = blockIdx.y;
    const int wid = tid >> 6, lane = tid & 63;
    const int wr = wid >> 1, wc = wid & 1;
    const int lg = lane >> 4, lr = lane & 15;

    f32x4 acc[4][4] = {};

    const int ar = tid >> 2, ac = (tid & 3) << 3;   // staging: row, col8

    for (int kb = 0; kb < K; kb += 32) {
        {
            const u16* ga = A + (size_t)(brow * 128 + ar) * K + kb + ac;
            *(uint4*)(&As[ar * 40 + ac]) = *(const uint4*)ga;
            *(uint4*)(&As[(ar + 64) * 40 + ac]) = *(const uint4*)(ga + (size_t)64 * K);
            const u16* gb = BT + (size_t)(bcol * 128 + ar) * K + kb + ac;
            *(uint4*)(&Bs[ar * 40 + ac]) = *(const uint4*)gb;
            *(uint4*)(&Bs[(ar + 64) * 40 + ac]) = *(const uint4*)(gb + (size_t)64 * K);
        }
        __syncthreads();

        bf16x8 aF[4], bF[4];
#pragma unroll
        for (int m = 0; m < 4; m++)
            aF[m] = *(const bf16x8*)(&As[(wr * 64 + m * 16 + lr) * 40 + lg * 8]);
#pragma unroll
        for (int n = 0; n < 4; n++)
            bF[n] = *(const bf16x8*)(&Bs[(wc * 64 + n * 16 + lr) * 40 + lg * 8]);
#pragma unroll
        for (int m = 0; m < 4; m++)
#pragma unroll
            for (int n = 0; n < 4; n++)
                acc[m][n] = __builtin_amdgcn_mfma_f32_16x16x32_bf16(aF[m], bF[n], acc[m][n], 0, 0, 0);
        __syncthreads();
    }

#pragma unroll
    for (int m = 0; m < 4; m++) {
#pragma unroll
        for (int n = 0; n < 4; n++) {
            if constexpr (OUT_VT) {
                int col = bcol * 128 + wc * 64 + n * 16 + lr;
                int row0 = brow * 128 + wr * 64 + m * 16 + lg * 4;
                union { u16 s[4]; unsigned long long q; } pk;
#pragma unroll
                for (int j = 0; j < 4; j++) pk.s[j] = f2b(acc[m][n][j]);
                *(unsigned long long*)(&((u16*)Cp)[(size_t)col * T_SEQ + row0]) = pk.q;
            } else {
#pragma unroll
                for (int j = 0; j < 4; j++) {
                    int row = brow * 128 + wr * 64 + m * 16 + lg * 4 + j;
                    int col = bcol * 128 + wc * 64 + n * 16 + lr;
                    ((float*)Cp)[(size_t)row * N + col] = acc[m][n][j];
                }
            }
        }
    }
}

// ---------------- fallback GEMM (f32 B, non-transposed) — LM head only ----------------
__device__ __forceinline__ int bs_off(int c, int k) {
    return c * 40 + ((((k >> 3) ^ ((c >> 3) & 3)) << 3) | (k & 7));
}

__global__ __launch_bounds__(256) void gemm_f32b_kernel(const u16* __restrict__ A,
                                                        const float* __restrict__ B,
                                                        float* __restrict__ C,
                                                        int N, int K) {
    __shared__ __align__(16) u16 As[128 * 40];
    __shared__ __align__(16) u16 Bs[128 * 40];
    const int tid = threadIdx.x;
    const int brow = blockIdx.y, bcol = blockIdx.x;
    const int wid = tid >> 6, lane = tid & 63;
    const int wr = wid >> 1, wc = wid & 1;
    const int lg = lane >> 4, lr = lane & 15;

    f32x4 acc[4][4] = {};
    const int ar = tid >> 2, ac = (tid & 3) << 3;
    const int bk = tid >> 4, bc = (tid & 15) << 3;

    for (int kb = 0; kb < K; kb += 32) {
        {
            const u16* ga = A + (size_t)(brow * 128 + ar) * K + kb + ac;
            *(uint4*)(&As[ar * 40 + ac]) = *(const uint4*)ga;
            *(uint4*)(&As[(ar + 64) * 40 + ac]) = *(const uint4*)(ga + (size_t)64 * K);
        }
        {
            const float* gb = B + (size_t)(kb + bk) * N + bcol * 128 + bc;
            float4 a0 = *(const float4*)gb;
            float4 a1 = *(const float4*)(gb + 4);
            float4 b0 = *(const float4*)(gb + (size_t)16 * N);
            float4 b1 = *(const float4*)(gb + (size_t)16 * N + 4);
            float f0[8] = {a0.x, a0.y, a0.z, a0.w, a1.x, a1.y, a1.z, a1.w};
            float f1[8] = {b0.x, b0.y, b0.z, b0.w, b1.x, b1.y, b1.z, b1.w};
#pragma unroll
            for (int i = 0; i < 8; i++) {
                Bs[bs_off(bc + i, bk)] = f2b(f0[i]);
                Bs[bs_off(bc + i, bk + 16)] = f2b(f1[i]);
            }
        }
        __syncthreads();

        bf16x8 aF[4], bF[4];
#pragma unroll
        for (int m = 0; m < 4; m++)
            aF[m] = *(const bf16x8*)(&As[(wr * 64 + m * 16 + lr) * 40 + lg * 8]);
#pragma unroll
        for (int n = 0; n < 4; n++) {
            int c = wc * 64 + n * 16 + lr;
            bF[n] = *(const bf16x8*)(&Bs[c * 40 + ((lg ^ ((c >> 3) & 3)) << 3)]);
        }
#pragma unroll
        for (int m = 0; m < 4; m++)
#pragma unroll
            for (int n = 0; n < 4; n++)
                acc[m][n] = __builtin_amdgcn_mfma_f32_16x16x32_bf16(aF[m], bF[n], acc[m][n], 0, 0, 0);
        __syncthreads();
    }

#pragma unroll
    for (int m = 0; m < 4; m++)
#pragma unroll
        for (int n = 0; n < 4; n++)
#pragma unroll
            for (int j = 0; j < 4; j++) {
                int row = brow * 128 + wr * 64 + m * 16 + lg * 4 + j;
                int col = bcol * 128 + wc * 64 + n * 16 + lr;
                C[(size_t)row * N + col] = acc[m][n][j];
            }
}

// ---------------- RoPE (f32 in -> bf16 out) ----------------
__global__ __launch_bounds__(256) void rope_kernel(const float* __restrict__ in,
                                                   u16* __restrict__ out, int heads) {
    int idx = blockIdx.x * 256 + threadIdx.x;
    int total = T_SEQ * heads * 32;
    if (idx >= total) return;
    int i = idx & 31;
    int rest = idx >> 5;
    int t = rest / heads;
    float inv = expf(-(float)i * (9.210340371976184f / 32.0f));
    float ang = (float)t * inv;
    float c = cosf(ang), s = sinf(ang);
    size_t base = (size_t)rest * HEAD_DIM + 2 * i;
    float x0 = in[base], x1 = in[base + 1];
    out[base]     = f2b(x0 * c - x1 * s);
    out[base + 1] = f2b(x0 * s + x1 * c);
}

// ---------------- flash attention ----------------
__global__ __launch_bounds__(256) void fattn_kernel(const u16* __restrict__ q,
                                                    const u16* __restrict__ k,
                                                    const u16* __restrict__ vt,
                                                    u16* __restrict__ out) {
    __shared__ __align__(16) u16 Ks[KBLK * KSS];
    __shared__ __align__(16) u16 Vt[HEAD_DIM * VTS];
    __shared__ __align__(16) u16 Ps[QBLK * PSS];
    const int tid = threadIdx.x;
    const int qb0 = blockIdx.x * QBLK, h = blockIdx.y, kvh = h >> 2;
    const int w = tid >> 6, lane = tid & 63;
    const int lg = lane >> 4, lr = lane & 15;

    bf16x8 qf0, qf1;
    {
        const u16* src = q + ((size_t)(qb0 + w * 16 + lr) * NH + h) * HEAD_DIM;
        qf0 = *(const bf16x8*)(src + lg * 8);
        qf1 = *(const bf16x8*)(src + 32 + lg * 8);
    }

    f32x4 acc_o[4] = {};
    float m_run[4] = {-1e30f, -1e30f, -1e30f, -1e30f};
    float l_run[4] = {0.f, 0.f, 0.f, 0.f};

    const int ntiles = (qb0 + QBLK - 1) / KBLK + 1;

    for (int kt = 0; kt < ntiles; kt++) {
        const int kb = kt * KBLK;
        __syncthreads();
        for (int c = tid; c < KBLK * 8; c += 256) {
            int row = c >> 3, c8 = (c & 7) << 3;
            *(uint4*)(&Ks[row * KSS + c8]) =
                *(const uint4*)(k + ((size_t)(kb + row) * NKV + kvh) * HEAD_DIM + c8);
        }
        for (int c = tid; c < HEAD_DIM * 16; c += 256) {
            int d = c >> 4, c16 = (c & 15) << 3;
            *(uint4*)(&Vt[d * VTS + c16]) =
                *(const uint4*)(vt + (size_t)(kvh * HEAD_DIM + d) * T_SEQ + kb + c16);
        }
        __syncthreads();

        f32x4 s[8] = {};
#pragma unroll
        for (int n = 0; n < 8; n++) {
            bf16x8 kf0 = *(const bf16x8*)(&Ks[(n * 16 + lr) * KSS + lg * 8]);
            bf16x8 kf1 = *(const bf16x8*)(&Ks[(n * 16 + lr) * KSS + 32 + lg * 8]);
            s[n] = __builtin_amdgcn_mfma_f32_16x16x32_bf16(qf0, kf0, s[n], 0, 0, 0);
            s[n] = __builtin_amdgcn_mfma_f32_16x16x32_bf16(qf1, kf1, s[n], 0, 0, 0);
        }

#pragma unroll
        for (int j = 0; j < 4; j++) {
            int q_g = qb0 + w * 16 + lg * 4 + j;
            float sv[8];
            float tmax = -1e30f;
#pragma unroll
            for (int n = 0; n < 8; n++) {
                float xx = s[n][j] * 0.125f;
                if (kb + n * 16 + lr > q_g) xx = -1e30f;
                sv[n] = xx;
                tmax = fmaxf(tmax, xx);
            }
#pragma unroll
            for (int mm = 1; mm < 16; mm <<= 1) tmax = fmaxf(tmax, __shfl_xor(tmax, mm));
            float mn = fmaxf(m_run[j], tmax);
            float sc = __expf(m_run[j] - mn);
            m_run[j] = mn;
            float rsum = 0.f;
#pragma unroll
            for (int n = 0; n < 8; n++) {
                float p = __expf(sv[n] - mn);
                rsum += p;
                Ps[(w * 16 + lg * 4 + j) * PSS + n * 16 + lr] = f2b(p);
            }
#pragma unroll
            for (int mm = 1; mm < 16; mm <<= 1) rsum += __shfl_xor(rsum, mm);
            l_run[j] = l_run[j] * sc + rsum;
#pragma unroll
            for (int n = 0; n < 4; n++) acc_o[n][j] *= sc;
        }

#pragma unroll
        for (int ks = 0; ks < 4; ks++) {
            bf16x8 pf = *(const bf16x8*)(&Ps[(w * 16 + lr) * PSS + ks * 32 + lg * 8]);
#pragma unroll
            for (int n = 0; n < 4; n++) {
                bf16x8 vf = *(const bf16x8*)(&Vt[(n * 16 + lr) * VTS + ks * 32 + lg * 8]);
                acc_o[n] = __builtin_amdgcn_mfma_f32_16x16x32_bf16(pf, vf, acc_o[n], 0, 0, 0);
            }
        }
    }

#pragma unroll
    for (int n = 0; n < 4; n++)
#pragma unroll
        for (int j = 0; j < 4; j++) {
            int t = qb0 + w * 16 + lg * 4 + j;
            int d = n * 16 + lr;
            out[((size_t)t * NH + h) * HEAD_DIM + d] = f2b(acc_o[n][j] / l_run[j]);
        }
}

// ---------------- silu(gate) * up -> bf16 ----------------
__global__ __launch_bounds__(256) void silu_mul_kernel(const float* __restrict__ g,
                                                       const float* __restrict__ u,
                                                       u16* __restrict__ out, int n) {
    int i = blockIdx.x * 256 + threadIdx.x;
    if (i < n) {
        float gv = g[i];
        float s = gv / (1.f + __expf(-gv));
        out[i] = f2b(s * u[i]);
    }
}

// ---------------- residual add ----------------
__global__ __launch_bounds__(256) void add_kernel(float* __restrict__ x,
                                                  const float* __restrict__ y, int n) {
    int i = blockIdx.x * 256 + threadIdx.x;
    if (i < n) x[i] += y[i];
}

// ---------------- host launch ----------------
extern "C" void kernel_launch(void* const* d_in, const int* in_sizes, int n_in,
                              void* d_out, int out_size, void* d_ws, size_t ws_size,
                              hipStream_t stream) {
    const int*   toks = (const int*)d_in[0];
    const float* emb  = (const float*)d_in[1];
    const float* Wq   = (const float*)d_in[2];
    const float* Wk   = (const float*)d_in[3];
    const float* Wv   = (const float*)d_in[4];
    const float* Wo   = (const float*)d_in[5];
    const float* Wg   = (const float*)d_in[6];
    const float* Wu   = (const float*)d_in[7];
    const float* Wd   = (const float*)d_in[8];
    const float* ln1  = (const float*)d_in[9];
    const float* ln2  = (const float*)d_in[10];
    const float* nw   = (const float*)d_in[11];
    const float* Wlm  = (const float*)d_in[12];

    // ---- scratch layout in d_out (262MB, all dead before LM head writes) ----
    char* ob = (char*)d_out;
    const size_t MB = 1024 * 1024;
    float* x   = (float*)(ob + 0 * MB);
    float* fA  = (float*)(ob + 8 * MB);
    float* fB  = (float*)(ob + 32 * MB);
    u16* vt    = (u16*)  (ob + 56 * MB);
    u16* qb    = (u16*)  (ob + 58 * MB);
    u16* kb    = (u16*)  (ob + 62 * MB);
    u16* attnb = (u16*)  (ob + 64 * MB);
    u16* ffb   = (u16*)  (ob + 68 * MB);
    // bf16 transposed weights at 80MB+ (45MB)
    size_t woff = 80 * MB;
    auto walloc = [&](size_t elems) {
        u16* p = (u16*)(ob + woff);
        woff += ((elems * 2 + 255) & ~(size_t)255);
        return p;
    };
    u16 *WqT[2], *WkT[2], *WvT[2], *WoT[2], *WgT[2], *WuT[2], *WdT[2];
    for (int l = 0; l < 2; l++) {
        WqT[l] = walloc((size_t)DMODEL * NH * HEAD_DIM);
        WkT[l] = walloc((size_t)DMODEL * NKV * HEAD_DIM);
        WvT[l] = walloc((size_t)DMODEL * NKV * HEAD_DIM);
        WoT[l] = walloc((size_t)NH * HEAD_DIM * DMODEL);
        WgT[l] = walloc((size_t)DMODEL * FFDIM);
        WuT[l] = walloc((size_t)DMODEL * FFDIM);
        WdT[l] = walloc((size_t)FFDIM * DMODEL);
    }
    u16* h = (u16*)d_ws;   // 4MB bf16 [T,D]
    bool ws_big = ws_size >= 72 * MB;
    u16* WlmT = ws_big ? (u16*)((char*)d_ws + 4 * MB) : nullptr;  // [NVOCAB][DMODEL] bf16
    (void)in_sizes; (void)n_in; (void)out_size;

    dim3 blk(256);
    auto tcast = [&](const float* in, u16* out, int K, int N) {
        tcast_kernel<<<dim3(N / 32, K / 32), blk, 0, stream>>>(in, out, K, N);
    };
    auto gemm_bt = [&](const u16* A, const u16* BT, float* C, int N, int K) {
        dim3 g(T_SEQ / 128, N / 128);
        gemm_bt_kernel<false><<<g, blk, 0, stream>>>(A, BT, (void*)C, N, K);
    };

    // ---- one-time weight transpose-casts ----
    for (int l = 0; l < 2; l++) {
        tcast(Wq + (size_t)l * DMODEL * NH * HEAD_DIM,  WqT[l], DMODEL, NH * HEAD_DIM);
        tcast(Wk + (size_t)l * DMODEL * NKV * HEAD_DIM, WkT[l], DMODEL, NKV * HEAD_DIM);
        tcast(Wv + (size_t)l * DMODEL * NKV * HEAD_DIM, WvT[l], DMODEL, NKV * HEAD_DIM);
        tcast(Wo + (size_t)l * NH * HEAD_DIM * DMODEL,  WoT[l], NH * HEAD_DIM, DMODEL);
        tcast(Wg + (size_t)l * DMODEL * FFDIM,          WgT[l], DMODEL, FFDIM);
        tcast(Wu + (size_t)l * DMODEL * FFDIM,          WuT[l], DMODEL, FFDIM);
        tcast(Wd + (size_t)l * FFDIM * DMODEL,          WdT[l], FFDIM, DMODEL);
    }
    if (WlmT) tcast(Wlm, WlmT, DMODEL, NVOCAB);

    embed_kernel<<<dim3(T_SEQ * DMODEL / 256), blk, 0, stream>>>(toks, emb, x);

    for (int l = 0; l < 2; l++) {
        // attn block
        rmsnorm_kernel<<<dim3(T_SEQ), blk, 0, stream>>>(x, ln1 + (size_t)l * DMODEL, h);
        gemm_bt(h, WqT[l], fA, NH * HEAD_DIM, DMODEL);
        gemm_bt(h, WkT[l], fB, NKV * HEAD_DIM, DMODEL);
        {   // v -> vt (bf16, transposed)
            dim3 g(T_SEQ / 128, (NKV * HEAD_DIM) / 128);
            gemm_bt_kernel<true><<<g, blk, 0, stream>>>(h, WvT[l], (void*)vt,
                                                        NKV * HEAD_DIM, DMODEL);
        }
        rope_kernel<<<dim3(T_SEQ * NH * 32 / 256), blk, 0, stream>>>(fA, qb, NH);
        rope_kernel<<<dim3(T_SEQ * NKV * 32 / 256), blk, 0, stream>>>(fB, kb, NKV);
        fattn_kernel<<<dim3(T_SEQ / QBLK, NH), blk, 0, stream>>>(qb, kb, vt, attnb);
        gemm_bt(attnb, WoT[l], fA, DMODEL, NH * HEAD_DIM);
        add_kernel<<<dim3(T_SEQ * DMODEL / 256), blk, 0, stream>>>(x, fA, T_SEQ * DMODEL);

        // ffn block
        rmsnorm_kernel<<<dim3(T_SEQ), blk, 0, stream>>>(x, ln2 + (size_t)l * DMODEL, h);
        gemm_bt(h, WgT[l], fA, FFDIM, DMODEL);
        gemm_bt(h, WuT[l], fB, FFDIM, DMODEL);
        silu_mul_kernel<<<dim3(T_SEQ * FFDIM / 256), blk, 0, stream>>>(fA, fB, ffb, T_SEQ * FFDIM);
        gemm_bt(ffb, WdT[l], fA, DMODEL, FFDIM);
        add_kernel<<<dim3(T_SEQ * DMODEL / 256), blk, 0, stream>>>(x, fA, T_SEQ * DMODEL);
    }

    // final norm + lm head
    rmsnorm_kernel<<<dim3(T_SEQ), blk, 0, stream>>>(x, nw, h);
    if (WlmT) {
        dim3 g(T_SEQ / 128, NVOCAB / 128);
        gemm_bt_kernel<false><<<g, blk, 0, stream>>>(h, WlmT, d_out, NVOCAB, DMODEL);
    } else {
        dim3 g(NVOCAB / 128, T_SEQ / 128);
        gemm_f32b_kernel<<<g, blk, 0, stream>>>(h, Wlm, (float*)d_out, NVOCAB, DMODEL);
    }
}

// Round 8
// 906.919 us; speedup vs baseline: 4.0362x; 1.1976x over previous
//
#include <hip/hip_runtime.h>

// ---------------- constants ----------------
#define T_SEQ 2048
#define DMODEL 1024
#define NH 16
#define NKV 4
#define HEAD_DIM 64
#define FFDIM 2816
#define NVOCAB 32000

// flash-attn tile params
#define QBLK 64
#define KBLK 128
#define KSS 72
#define VTS 136
#define PSS 136

using u16 = unsigned short;
typedef __bf16 bf16x8 __attribute__((ext_vector_type(8)));
typedef float f32x4 __attribute__((ext_vector_type(4)));

__device__ __forceinline__ float b2f(u16 u) {
    union { unsigned int i; float f; } v; v.i = ((unsigned int)u) << 16; return v.f;
}
__device__ __forceinline__ u16 f2b(float f) {
    unsigned int u = __builtin_bit_cast(unsigned int, f);
    unsigned int r = (u + 0x7FFFu + ((u >> 16) & 1u)) >> 16;
    return (u16)r;
}
// async global->LDS, 16B per lane; LDS dest = wave-uniform base + lane*16
__device__ __forceinline__ void gload16(const u16* g, u16* l) {
    __builtin_amdgcn_global_load_lds(
        (const __attribute__((address_space(1))) void*)g,
        (__attribute__((address_space(3))) void*)l, 16, 0, 0);
}

// ---------------- embedding gather ----------------
__global__ __launch_bounds__(256) void embed_kernel(const int* __restrict__ toks,
                                                    const float* __restrict__ emb,
                                                    float* __restrict__ x) {
    int idx = blockIdx.x * 256 + threadIdx.x;
    int t = idx >> 10, d = idx & 1023;
    x[idx] = emb[(size_t)toks[t] * DMODEL + d];
}

// ---------------- rmsnorm: f32 in -> bf16 out ----------------
__global__ __launch_bounds__(256) void rmsnorm_kernel(const float* __restrict__ x,
                                                      const float* __restrict__ w,
                                                      u16* __restrict__ out) {
    __shared__ float red[256];
    const int row = blockIdx.x, tid = threadIdx.x;
    const float* xr = x + (size_t)row * DMODEL;
    float vals[4]; float ss = 0.f;
#pragma unroll
    for (int i = 0; i < 4; i++) { float v = xr[tid + 256 * i]; vals[i] = v; ss += v * v; }
    red[tid] = ss; __syncthreads();
    for (int s = 128; s > 0; s >>= 1) { if (tid < s) red[tid] += red[tid + s]; __syncthreads(); }
    float inv = rsqrtf(red[0] * (1.0f / DMODEL) + 1e-5f);
#pragma unroll
    for (int i = 0; i < 4; i++) {
        int c = tid + 256 * i;
        out[(size_t)row * DMODEL + c] = f2b(vals[i] * inv * w[c]);
    }
}

// ---------------- transpose-cast: in[K][N] f32 -> out[N][K] bf16 ----------------
__global__ __launch_bounds__(256) void tcast_kernel(const float* __restrict__ in,
                                                    u16* __restrict__ out, int K, int N) {
    __shared__ float tile[32][33];
    int bx = blockIdx.x * 32;  // N
    int by = blockIdx.y * 32;  // K
    int tx = threadIdx.x & 31, ty = threadIdx.x >> 5;
#pragma unroll
    for (int i = 0; i < 32; i += 8)
        tile[ty + i][tx] = in[(size_t)(by + ty + i) * N + bx + tx];
    __syncthreads();
#pragma unroll
    for (int i = 0; i < 32; i += 8)
        out[(size_t)(bx + ty + i) * K + by + tx] = f2b(tile[tx][ty + i]);
}

// ---------------- strided transpose-cast for V: fqkv[:,1280:1536] -> vt[256][T] ----------------
__global__ __launch_bounds__(256) void vtcast_kernel(const float* __restrict__ fqkv,
                                                     u16* __restrict__ vt) {
    __shared__ float tile[32][33];
    int bx = blockIdx.x * 32;  // v-dim (0..255)
    int by = blockIdx.y * 32;  // t
    int tx = threadIdx.x & 31, ty = threadIdx.x >> 5;
#pragma unroll
    for (int i = 0; i < 32; i += 8)
        tile[ty + i][tx] = fqkv[(size_t)(by + ty + i) * 1536 + 1280 + bx + tx];
    __syncthreads();
#pragma unroll
    for (int i = 0; i < 32; i += 8)
        vt[(size_t)(bx + ty + i) * T_SEQ + by + tx] = f2b(tile[tx][ty + i]);
}

// ---------------- GEMM-BT: C[M,N](f32) = A[M,K](bf16) * BT[N,K](bf16) ----------------
// Tile 128x128, BK=32, 4 waves (2x2). m97-style staging: global_load_lds(16B)
// directly into LINEAR [128][32] LDS tiles (no pad). Wave w stages rows
// [32w,32w+32) of both tiles (2 instructions each). Grid: x = M-tiles (fast)
// so consecutive blocks share one BT panel (L2 reuse).
__global__ __launch_bounds__(256) void gemm_bt_kernel(const u16* __restrict__ A,
                                                      const u16* __restrict__ BT,
                                                      float* __restrict__ C,
                                                      int N, int K) {
    __shared__ __align__(16) u16 As[128 * 32];
    __shared__ __align__(16) u16 Bs[128 * 32];
    const int tid = threadIdx.x;
    const int brow = blockIdx.x, bcol = blockIdx.y;
    const int w = tid >> 6, lane = tid & 63;
    const int wr = w >> 1, wc = w & 1;
    const int lg = lane >> 4, lr = lane & 15;

    f32x4 acc[4][4] = {};

    // staging: lane -> row w*32 + (lane>>2) (+16 for 2nd inst), col8 = (lane&3)*8
    const int srow = w * 32 + (lane >> 2);
    const int scol = (lane & 3) << 3;
    const u16* gA = A + (size_t)(brow * 128 + srow) * K + scol;
    const u16* gB = BT + (size_t)(bcol * 128 + srow) * K + scol;
    u16* lA0 = &As[(w * 32) * 32];
    u16* lA1 = &As[(w * 32 + 16) * 32];
    u16* lB0 = &Bs[(w * 32) * 32];
    u16* lB1 = &Bs[(w * 32 + 16) * 32];

    for (int kb = 0; kb < K; kb += 32) {
        gload16(gA + kb, lA0);
        gload16(gA + (size_t)16 * K + kb, lA1);
        gload16(gB + kb, lB0);
        gload16(gB + (size_t)16 * K + kb, lB1);
        __syncthreads();

        bf16x8 aF[4], bF[4];
#pragma unroll
        for (int m = 0; m < 4; m++)
            aF[m] = *(const bf16x8*)(&As[(wr * 64 + m * 16 + lr) * 32 + lg * 8]);
#pragma unroll
        for (int n = 0; n < 4; n++)
            bF[n] = *(const bf16x8*)(&Bs[(wc * 64 + n * 16 + lr) * 32 + lg * 8]);
#pragma unroll
        for (int m = 0; m < 4; m++)
#pragma unroll
            for (int n = 0; n < 4; n++)
                acc[m][n] = __builtin_amdgcn_mfma_f32_16x16x32_bf16(aF[m], bF[n], acc[m][n], 0, 0, 0);
        __syncthreads();
    }

#pragma unroll
    for (int m = 0; m < 4; m++)
#pragma unroll
        for (int n = 0; n < 4; n++)
#pragma unroll
            for (int j = 0; j < 4; j++) {
                int row = brow * 128 + wr * 64 + m * 16 + lg * 4 + j;
                int col = bcol * 128 + wc * 64 + n * 16 + lr;
                C[(size_t)row * N + col] = acc[m][n][j];
            }
}

// ---------------- fallback GEMM (f32 B, non-transposed) — LM head only ----------------
__device__ __forceinline__ int bs_off(int c, int k) {
    return c * 40 + ((((k >> 3) ^ ((c >> 3) & 3)) << 3) | (k & 7));
}

__global__ __launch_bounds__(256) void gemm_f32b_kernel(const u16* __restrict__ A,
                                                        const float* __restrict__ B,
                                                        float* __restrict__ C,
                                                        int N, int K) {
    __shared__ __align__(16) u16 As[128 * 40];
    __shared__ __align__(16) u16 Bs[128 * 40];
    const int tid = threadIdx.x;
    const int brow = blockIdx.y, bcol = blockIdx.x;
    const int wid = tid >> 6, lane = tid & 63;
    const int wr = wid >> 1, wc = wid & 1;
    const int lg = lane >> 4, lr = lane & 15;

    f32x4 acc[4][4] = {};
    const int ar = tid >> 2, ac = (tid & 3) << 3;
    const int bk = tid >> 4, bc = (tid & 15) << 3;

    for (int kb = 0; kb < K; kb += 32) {
        {
            const u16* ga = A + (size_t)(brow * 128 + ar) * K + kb + ac;
            *(uint4*)(&As[ar * 40 + ac]) = *(const uint4*)ga;
            *(uint4*)(&As[(ar + 64) * 40 + ac]) = *(const uint4*)(ga + (size_t)64 * K);
        }
        {
            const float* gb = B + (size_t)(kb + bk) * N + bcol * 128 + bc;
            float4 a0 = *(const float4*)gb;
            float4 a1 = *(const float4*)(gb + 4);
            float4 b0 = *(const float4*)(gb + (size_t)16 * N);
            float4 b1 = *(const float4*)(gb + (size_t)16 * N + 4);
            float f0[8] = {a0.x, a0.y, a0.z, a0.w, a1.x, a1.y, a1.z, a1.w};
            float f1[8] = {b0.x, b0.y, b0.z, b0.w, b1.x, b1.y, b1.z, b1.w};
#pragma unroll
            for (int i = 0; i < 8; i++) {
                Bs[bs_off(bc + i, bk)] = f2b(f0[i]);
                Bs[bs_off(bc + i, bk + 16)] = f2b(f1[i]);
            }
        }
        __syncthreads();

        bf16x8 aF[4], bF[4];
#pragma unroll
        for (int m = 0; m < 4; m++)
            aF[m] = *(const bf16x8*)(&As[(wr * 64 + m * 16 + lr) * 40 + lg * 8]);
#pragma unroll
        for (int n = 0; n < 4; n++) {
            int c = wc * 64 + n * 16 + lr;
            bF[n] = *(const bf16x8*)(&Bs[c * 40 + ((lg ^ ((c >> 3) & 3)) << 3)]);
        }
#pragma unroll
        for (int m = 0; m < 4; m++)
#pragma unroll
            for (int n = 0; n < 4; n++)
                acc[m][n] = __builtin_amdgcn_mfma_f32_16x16x32_bf16(aF[m], bF[n], acc[m][n], 0, 0, 0);
        __syncthreads();
    }

#pragma unroll
    for (int m = 0; m < 4; m++)
#pragma unroll
        for (int n = 0; n < 4; n++)
#pragma unroll
            for (int j = 0; j < 4; j++) {
                int row = brow * 128 + wr * 64 + m * 16 + lg * 4 + j;
                int col = bcol * 128 + wc * 64 + n * 16 + lr;
                C[(size_t)row * N + col] = acc[m][n][j];
            }
}

// ---------------- RoPE: f32 strided in -> bf16 packed out ----------------
__global__ __launch_bounds__(256) void rope_kernel(const float* __restrict__ in,
                                                   u16* __restrict__ out, int heads,
                                                   int instride, int incoloff) {
    int idx = blockIdx.x * 256 + threadIdx.x;
    int total = T_SEQ * heads * 32;
    if (idx >= total) return;
    int i = idx & 31;
    int rest = idx >> 5;       // t*heads + h
    int t = rest / heads, hh = rest - t * heads;
    float inv = expf(-(float)i * (9.210340371976184f / 32.0f));
    float ang = (float)t * inv;
    float c = cosf(ang), s = sinf(ang);
    size_t src = (size_t)t * instride + incoloff + hh * HEAD_DIM + 2 * i;
    size_t dst = (size_t)rest * HEAD_DIM + 2 * i;
    float x0 = in[src], x1 = in[src + 1];
    out[dst]     = f2b(x0 * c - x1 * s);
    out[dst + 1] = f2b(x0 * s + x1 * c);
}

// ---------------- flash attention ----------------
__global__ __launch_bounds__(256) void fattn_kernel(const u16* __restrict__ q,
                                                    const u16* __restrict__ k,
                                                    const u16* __restrict__ vt,
                                                    u16* __restrict__ out) {
    __shared__ __align__(16) u16 Ks[KBLK * KSS];
    __shared__ __align__(16) u16 Vt[HEAD_DIM * VTS];
    __shared__ __align__(16) u16 Ps[QBLK * PSS];
    const int tid = threadIdx.x;
    const int qb0 = blockIdx.x * QBLK, h = blockIdx.y, kvh = h >> 2;
    const int w = tid >> 6, lane = tid & 63;
    const int lg = lane >> 4, lr = lane & 15;

    bf16x8 qf0, qf1;
    {
        const u16* src = q + ((size_t)(qb0 + w * 16 + lr) * NH + h) * HEAD_DIM;
        qf0 = *(const bf16x8*)(src + lg * 8);
        qf1 = *(const bf16x8*)(src + 32 + lg * 8);
    }

    f32x4 acc_o[4] = {};
    float m_run[4] = {-1e30f, -1e30f, -1e30f, -1e30f};
    float l_run[4] = {0.f, 0.f, 0.f, 0.f};

    const int ntiles = (qb0 + QBLK - 1) / KBLK + 1;

    for (int kt = 0; kt < ntiles; kt++) {
        const int kb = kt * KBLK;
        __syncthreads();
        for (int c = tid; c < KBLK * 8; c += 256) {
            int row = c >> 3, c8 = (c & 7) << 3;
            *(uint4*)(&Ks[row * KSS + c8]) =
                *(const uint4*)(k + ((size_t)(kb + row) * NKV + kvh) * HEAD_DIM + c8);
        }
        for (int c = tid; c < HEAD_DIM * 16; c += 256) {
            int d = c >> 4, c16 = (c & 15) << 3;
            *(uint4*)(&Vt[d * VTS + c16]) =
                *(const uint4*)(vt + (size_t)(kvh * HEAD_DIM + d) * T_SEQ + kb + c16);
        }
        __syncthreads();

        f32x4 s[8] = {};
#pragma unroll
        for (int n = 0; n < 8; n++) {
            bf16x8 kf0 = *(const bf16x8*)(&Ks[(n * 16 + lr) * KSS + lg * 8]);
            bf16x8 kf1 = *(const bf16x8*)(&Ks[(n * 16 + lr) * KSS + 32 + lg * 8]);
            s[n] = __builtin_amdgcn_mfma_f32_16x16x32_bf16(qf0, kf0, s[n], 0, 0, 0);
            s[n] = __builtin_amdgcn_mfma_f32_16x16x32_bf16(qf1, kf1, s[n], 0, 0, 0);
        }

#pragma unroll
        for (int j = 0; j < 4; j++) {
            int q_g = qb0 + w * 16 + lg * 4 + j;
            float sv[8];
            float tmax = -1e30f;
#pragma unroll
            for (int n = 0; n < 8; n++) {
                float xx = s[n][j] * 0.125f;
                if (kb + n * 16 + lr > q_g) xx = -1e30f;
                sv[n] = xx;
                tmax = fmaxf(tmax, xx);
            }
#pragma unroll
            for (int mm = 1; mm < 16; mm <<= 1) tmax = fmaxf(tmax, __shfl_xor(tmax, mm));
            float mn = fmaxf(m_run[j], tmax);
            float sc = __expf(m_run[j] - mn);
            m_run[j] = mn;
            float rsum = 0.f;
#pragma unroll
            for (int n = 0; n < 8; n++) {
                float p = __expf(sv[n] - mn);
                rsum += p;
                Ps[(w * 16 + lg * 4 + j) * PSS + n * 16 + lr] = f2b(p);
            }
#pragma unroll
            for (int mm = 1; mm < 16; mm <<= 1) rsum += __shfl_xor(rsum, mm);
            l_run[j] = l_run[j] * sc + rsum;
#pragma unroll
            for (int n = 0; n < 4; n++) acc_o[n][j] *= sc;
        }

#pragma unroll
        for (int ks = 0; ks < 4; ks++) {
            bf16x8 pf = *(const bf16x8*)(&Ps[(w * 16 + lr) * PSS + ks * 32 + lg * 8]);
#pragma unroll
            for (int n = 0; n < 4; n++) {
                bf16x8 vf = *(const bf16x8*)(&Vt[(n * 16 + lr) * VTS + ks * 32 + lg * 8]);
                acc_o[n] = __builtin_amdgcn_mfma_f32_16x16x32_bf16(pf, vf, acc_o[n], 0, 0, 0);
            }
        }
    }

#pragma unroll
    for (int n = 0; n < 4; n++)
#pragma unroll
        for (int j = 0; j < 4; j++) {
            int t = qb0 + w * 16 + lg * 4 + j;
            int d = n * 16 + lr;
            out[((size_t)t * NH + h) * HEAD_DIM + d] = f2b(acc_o[n][j] / l_run[j]);
        }
}

// ---------------- silu(gate)*up from packed fGU[t][5632] -> bf16 [t][2816] ----------------
__global__ __launch_bounds__(256) void silu_mul_kernel(const float* __restrict__ gu,
                                                       u16* __restrict__ out) {
    int t = blockIdx.x;
    int c = blockIdx.y * 256 + threadIdx.x;   // < 2816
    float gv = gu[(size_t)t * 5632 + c];
    float uv = gu[(size_t)t * 5632 + 2816 + c];
    float s = gv / (1.f + __expf(-gv));
    out[(size_t)t * FFDIM + c] = f2b(s * uv);
}

// ---------------- residual add ----------------
__global__ __launch_bounds__(256) void add_kernel(float* __restrict__ x,
                                                  const float* __restrict__ y, int n) {
    int i = blockIdx.x * 256 + threadIdx.x;
    if (i < n) x[i] += y[i];
}

// ---------------- host launch ----------------
extern "C" void kernel_launch(void* const* d_in, const int* in_sizes, int n_in,
                              void* d_out, int out_size, void* d_ws, size_t ws_size,
                              hipStream_t stream) {
    const int*   toks = (const int*)d_in[0];
    const float* emb  = (const float*)d_in[1];
    const float* Wq   = (const float*)d_in[2];
    const float* Wk   = (const float*)d_in[3];
    const float* Wv   = (const float*)d_in[4];
    const float* Wo   = (const float*)d_in[5];
    const float* Wg   = (const float*)d_in[6];
    const float* Wu   = (const float*)d_in[7];
    const float* Wd   = (const float*)d_in[8];
    const float* ln1  = (const float*)d_in[9];
    const float* ln2  = (const float*)d_in[10];
    const float* nw   = (const float*)d_in[11];
    const float* Wlm  = (const float*)d_in[12];

    // ---- scratch layout in d_out (262MB, all dead before LM head writes) ----
    char* ob = (char*)d_out;
    const size_t MB = 1024 * 1024;
    float* x    = (float*)(ob + 0 * MB);    // 8MB   residual [T,D]
    float* fqkv = (float*)(ob + 8 * MB);    // 12MB  [T,1536] qkv packed
    float* fGU  = (float*)(ob + 20 * MB);   // 44MB  [T,5632] gate|up packed
    float* fA   = (float*)(ob + 64 * MB);   // 8MB   [T,D] (attn-proj / down out)
    u16* vt     = (u16*)  (ob + 72 * MB);   // 1MB   V^T [256][T]
    u16* qb     = (u16*)  (ob + 74 * MB);   // 4MB
    u16* kb     = (u16*)  (ob + 78 * MB);   // 1MB
    u16* attnb  = (u16*)  (ob + 80 * MB);   // 4MB
    u16* ffb    = (u16*)  (ob + 84 * MB);   // 11.5MB
    size_t woff = 96 * MB;                  // packed bf16 transposed weights (43MB)
    auto walloc = [&](size_t elems) {
        u16* p = (u16*)(ob + woff);
        woff += ((elems * 2 + 255) & ~(size_t)255);
        return p;
    };
    u16 *WqkvT[2], *WoT[2], *WguT[2], *WdT[2];
    for (int l = 0; l < 2; l++) {
        WqkvT[l] = walloc((size_t)1536 * DMODEL);
        WoT[l]   = walloc((size_t)DMODEL * DMODEL);
        WguT[l]  = walloc((size_t)5632 * DMODEL);
        WdT[l]   = walloc((size_t)DMODEL * FFDIM);
    }
    u16* h = (u16*)d_ws;   // 4MB bf16 [T,D]
    bool ws_big = ws_size >= 72 * MB;
    u16* WlmT = ws_big ? (u16*)((char*)d_ws + 4 * MB) : nullptr;  // [NVOCAB][DMODEL]
    (void)in_sizes; (void)n_in; (void)out_size;

    dim3 blk(256);
    auto tcast = [&](const float* in, u16* out, int K, int N) {
        tcast_kernel<<<dim3(N / 32, K / 32), blk, 0, stream>>>(in, out, K, N);
    };
    auto gemm_bt = [&](const u16* A, const u16* BT, float* C, int N, int K) {
        dim3 g(T_SEQ / 128, N / 128);
        gemm_bt_kernel<<<g, blk, 0, stream>>>(A, BT, C, N, K);
    };

    // ---- one-time weight transpose-casts (packed) ----
    for (int l = 0; l < 2; l++) {
        tcast(Wq + (size_t)l * DMODEL * NH * HEAD_DIM,  WqkvT[l],                    DMODEL, NH * HEAD_DIM);
        tcast(Wk + (size_t)l * DMODEL * NKV * HEAD_DIM, WqkvT[l] + (size_t)1024 * DMODEL, DMODEL, NKV * HEAD_DIM);
        tcast(Wv + (size_t)l * DMODEL * NKV * HEAD_DIM, WqkvT[l] + (size_t)1280 * DMODEL, DMODEL, NKV * HEAD_DIM);
        tcast(Wo + (size_t)l * DMODEL * DMODEL,         WoT[l],  DMODEL, DMODEL);
        tcast(Wg + (size_t)l * DMODEL * FFDIM,          WguT[l],                     DMODEL, FFDIM);
        tcast(Wu + (size_t)l * DMODEL * FFDIM,          WguT[l] + (size_t)FFDIM * DMODEL, DMODEL, FFDIM);
        tcast(Wd + (size_t)l * FFDIM * DMODEL,          WdT[l],  FFDIM, DMODEL);
    }
    if (WlmT) tcast(Wlm, WlmT, DMODEL, NVOCAB);

    embed_kernel<<<dim3(T_SEQ * DMODEL / 256), blk, 0, stream>>>(toks, emb, x);

    for (int l = 0; l < 2; l++) {
        // attn block
        rmsnorm_kernel<<<dim3(T_SEQ), blk, 0, stream>>>(x, ln1 + (size_t)l * DMODEL, h);
        gemm_bt(h, WqkvT[l], fqkv, 1536, DMODEL);
        rope_kernel<<<dim3(T_SEQ * NH * 32 / 256), blk, 0, stream>>>(fqkv, qb, NH, 1536, 0);
        rope_kernel<<<dim3(T_SEQ * NKV * 32 / 256), blk, 0, stream>>>(fqkv, kb, NKV, 1536, 1024);
        vtcast_kernel<<<dim3(8, T_SEQ / 32), blk, 0, stream>>>(fqkv, vt);
        fattn_kernel<<<dim3(T_SEQ / QBLK, NH), blk, 0, stream>>>(qb, kb, vt, attnb);
        gemm_bt(attnb, WoT[l], fA, DMODEL, DMODEL);
        add_kernel<<<dim3(T_SEQ * DMODEL / 256), blk, 0, stream>>>(x, fA, T_SEQ * DMODEL);

        // ffn block
        rmsnorm_kernel<<<dim3(T_SEQ), blk, 0, stream>>>(x, ln2 + (size_t)l * DMODEL, h);
        gemm_bt(h, WguT[l], fGU, 5632, DMODEL);
        silu_mul_kernel<<<dim3(T_SEQ, FFDIM / 256), blk, 0, stream>>>(fGU, ffb);
        gemm_bt(ffb, WdT[l], fA, DMODEL, FFDIM);
        add_kernel<<<dim3(T_SEQ * DMODEL / 256), blk, 0, stream>>>(x, fA, T_SEQ * DMODEL);
    }

    // final norm + lm head
    rmsnorm_kernel<<<dim3(T_SEQ), blk, 0, stream>>>(x, nw, h);
    if (WlmT) {
        gemm_bt(h, WlmT, (float*)d_out, NVOCAB, DMODEL);
    } else {
        dim3 g(NVOCAB / 128, T_SEQ / 128);
        gemm_f32b_kernel<<<g, blk, 0, stream>>>(h, Wlm, (float*)d_out, NVOCAB, DMODEL);
    }
}

// Round 9
// 851.121 us; speedup vs baseline: 4.3009x; 1.0656x over previous
//
#include <hip/hip_runtime.h>

// ---------------- constants ----------------
#define T_SEQ 2048
#define DMODEL 1024
#define NH 16
#define NKV 4
#define HEAD_DIM 64
#define FFDIM 2816
#define NVOCAB 32000

// flash-attn tile params
#define QBLK 64
#define KBLK 128
#define KSS 72
#define VTS 136
#define PSS 136

using u16 = unsigned short;
typedef __bf16 bf16x8 __attribute__((ext_vector_type(8)));
typedef float f32x4 __attribute__((ext_vector_type(4)));

__device__ __forceinline__ float b2f(u16 u) {
    union { unsigned int i; float f; } v; v.i = ((unsigned int)u) << 16; return v.f;
}
__device__ __forceinline__ u16 f2b(float f) {
    unsigned int u = __builtin_bit_cast(unsigned int, f);
    unsigned int r = (u + 0x7FFFu + ((u >> 16) & 1u)) >> 16;
    return (u16)r;
}
// async global->LDS, 16B per lane; LDS dest = wave-uniform base + lane*16
__device__ __forceinline__ void gload16(const u16* g, u16* l) {
    __builtin_amdgcn_global_load_lds(
        (const __attribute__((address_space(1))) void*)g,
        (__attribute__((address_space(3))) void*)l, 16, 0, 0);
}

// ---------------- embedding gather ----------------
__global__ __launch_bounds__(256) void embed_kernel(const int* __restrict__ toks,
                                                    const float* __restrict__ emb,
                                                    float* __restrict__ x) {
    int idx = blockIdx.x * 256 + threadIdx.x;
    int t = idx >> 10, d = idx & 1023;
    x[idx] = emb[(size_t)toks[t] * DMODEL + d];
}

// ---------------- rmsnorm: f32 in -> bf16 out ----------------
__global__ __launch_bounds__(256) void rmsnorm_kernel(const float* __restrict__ x,
                                                      const float* __restrict__ w,
                                                      u16* __restrict__ out) {
    __shared__ float red[256];
    const int row = blockIdx.x, tid = threadIdx.x;
    const float* xr = x + (size_t)row * DMODEL;
    float vals[4]; float ss = 0.f;
#pragma unroll
    for (int i = 0; i < 4; i++) { float v = xr[tid + 256 * i]; vals[i] = v; ss += v * v; }
    red[tid] = ss; __syncthreads();
    for (int s = 128; s > 0; s >>= 1) { if (tid < s) red[tid] += red[tid + s]; __syncthreads(); }
    float inv = rsqrtf(red[0] * (1.0f / DMODEL) + 1e-5f);
#pragma unroll
    for (int i = 0; i < 4; i++) {
        int c = tid + 256 * i;
        out[(size_t)row * DMODEL + c] = f2b(vals[i] * inv * w[c]);
    }
}

// ---------------- transpose-cast: in[K][N] f32 -> out[N][K] bf16 ----------------
__global__ __launch_bounds__(256) void tcast_kernel(const float* __restrict__ in,
                                                    u16* __restrict__ out, int K, int N) {
    __shared__ float tile[32][33];
    int bx = blockIdx.x * 32;  // N
    int by = blockIdx.y * 32;  // K
    int tx = threadIdx.x & 31, ty = threadIdx.x >> 5;
#pragma unroll
    for (int i = 0; i < 32; i += 8)
        tile[ty + i][tx] = in[(size_t)(by + ty + i) * N + bx + tx];
    __syncthreads();
#pragma unroll
    for (int i = 0; i < 32; i += 8)
        out[(size_t)(bx + ty + i) * K + by + tx] = f2b(tile[tx][ty + i]);
}

// ---------------- strided transpose-cast for V: fqkv[:,1280:1536] -> vt[256][T] ----------------
__global__ __launch_bounds__(256) void vtcast_kernel(const float* __restrict__ fqkv,
                                                     u16* __restrict__ vt) {
    __shared__ float tile[32][33];
    int bx = blockIdx.x * 32;  // v-dim (0..255)
    int by = blockIdx.y * 32;  // t
    int tx = threadIdx.x & 31, ty = threadIdx.x >> 5;
#pragma unroll
    for (int i = 0; i < 32; i += 8)
        tile[ty + i][tx] = fqkv[(size_t)(by + ty + i) * 1536 + 1280 + bx + tx];
    __syncthreads();
#pragma unroll
    for (int i = 0; i < 32; i += 8)
        vt[(size_t)(bx + ty + i) * T_SEQ + by + tx] = f2b(tile[tx][ty + i]);
}

// ---------------- GEMM-BT: C[M,N](f32) = A[M,K](bf16) * BT[N,K](bf16) ----------------
// Tile 128x128, BK=32, 4 waves (2x2). Double-buffered m97-style staging:
// global_load_lds(16B) into linear [128][32] LDS; stage(t+1) issued BEFORE
// compute(t) so HBM/L2 latency hides under MFMA; one __syncthreads per K-step
// (its implicit vmcnt(0)+lgkmcnt(0) drain is the only sync needed).
// XCD-chunked bijective swizzle: all M-tiles sharing a BT panel land on one
// XCD's L2 (panel fetched from HBM ~once instead of ~8x).
__global__ __launch_bounds__(256) void gemm_bt_kernel(const u16* __restrict__ A,
                                                      const u16* __restrict__ BT,
                                                      float* __restrict__ C,
                                                      int N, int K) {
    __shared__ __align__(16) u16 As[2][128 * 32];
    __shared__ __align__(16) u16 Bs[2][128 * 32];
    const int tid = threadIdx.x;
    // XCD-chunked swizzle (m204 bijective form)
    const int gx = gridDim.x;
    const int nwg = gx * gridDim.y;
    const int hwid = blockIdx.y * gx + blockIdx.x;
    const int q = nwg >> 3, r = nwg & 7;
    const int xcd = hwid & 7, rem = hwid >> 3;
    const int wgid = (xcd < r ? xcd * (q + 1) : r * (q + 1) + (xcd - r) * q) + rem;
    const int brow = wgid % gx, bcol = wgid / gx;

    const int w = tid >> 6, lane = tid & 63;
    const int wr = w >> 1, wc = w & 1;
    const int lg = lane >> 4, lr = lane & 15;

    f32x4 acc[4][4] = {};

    // staging: wave w stages rows [32w,32w+32) of both tiles; lane->row w*32+(lane>>2), col8=(lane&3)*8
    const int srow = w * 32 + (lane >> 2);
    const int scol = (lane & 3) << 3;
    const u16* gA = A + (size_t)(brow * 128 + srow) * K + scol;
    const u16* gB = BT + (size_t)(bcol * 128 + srow) * K + scol;
    const int lofs0 = (w * 32) * 32;
    const int lofs1 = (w * 32 + 16) * 32;

    const int nt = K >> 5;
    // prologue: stage tile 0 into buf 0
    gload16(gA, &As[0][lofs0]);
    gload16(gA + (size_t)16 * K, &As[0][lofs1]);
    gload16(gB, &Bs[0][lofs0]);
    gload16(gB + (size_t)16 * K, &Bs[0][lofs1]);
    __syncthreads();

    int cur = 0;
    for (int t = 0; t < nt; t++) {
        if (t + 1 < nt) {
            const int kb = (t + 1) << 5;
            gload16(gA + kb, &As[cur ^ 1][lofs0]);
            gload16(gA + (size_t)16 * K + kb, &As[cur ^ 1][lofs1]);
            gload16(gB + kb, &Bs[cur ^ 1][lofs0]);
            gload16(gB + (size_t)16 * K + kb, &Bs[cur ^ 1][lofs1]);
        }
        bf16x8 aF[4], bF[4];
#pragma unroll
        for (int m = 0; m < 4; m++)
            aF[m] = *(const bf16x8*)(&As[cur][(wr * 64 + m * 16 + lr) * 32 + lg * 8]);
#pragma unroll
        for (int n = 0; n < 4; n++)
            bF[n] = *(const bf16x8*)(&Bs[cur][(wc * 64 + n * 16 + lr) * 32 + lg * 8]);
#pragma unroll
        for (int m = 0; m < 4; m++)
#pragma unroll
            for (int n = 0; n < 4; n++)
                acc[m][n] = __builtin_amdgcn_mfma_f32_16x16x32_bf16(aF[m], bF[n], acc[m][n], 0, 0, 0);
        __syncthreads();   // drains vmcnt (next-tile loads) + lgkmcnt (our ds_reads)
        cur ^= 1;
    }

#pragma unroll
    for (int m = 0; m < 4; m++)
#pragma unroll
        for (int n = 0; n < 4; n++)
#pragma unroll
            for (int j = 0; j < 4; j++) {
                int row = brow * 128 + wr * 64 + m * 16 + lg * 4 + j;
                int col = bcol * 128 + wc * 64 + n * 16 + lr;
                C[(size_t)row * N + col] = acc[m][n][j];
            }
}

// ---------------- fallback GEMM (f32 B, non-transposed) — LM head only ----------------
__device__ __forceinline__ int bs_off(int c, int k) {
    return c * 40 + ((((k >> 3) ^ ((c >> 3) & 3)) << 3) | (k & 7));
}

__global__ __launch_bounds__(256) void gemm_f32b_kernel(const u16* __restrict__ A,
                                                        const float* __restrict__ B,
                                                        float* __restrict__ C,
                                                        int N, int K) {
    __shared__ __align__(16) u16 As[128 * 40];
    __shared__ __align__(16) u16 Bs[128 * 40];
    const int tid = threadIdx.x;
    const int brow = blockIdx.y, bcol = blockIdx.x;
    const int wid = tid >> 6, lane = tid & 63;
    const int wr = wid >> 1, wc = wid & 1;
    const int lg = lane >> 4, lr = lane & 15;

    f32x4 acc[4][4] = {};
    const int ar = tid >> 2, ac = (tid & 3) << 3;
    const int bk = tid >> 4, bc = (tid & 15) << 3;

    for (int kb = 0; kb < K; kb += 32) {
        {
            const u16* ga = A + (size_t)(brow * 128 + ar) * K + kb + ac;
            *(uint4*)(&As[ar * 40 + ac]) = *(const uint4*)ga;
            *(uint4*)(&As[(ar + 64) * 40 + ac]) = *(const uint4*)(ga + (size_t)64 * K);
        }
        {
            const float* gb = B + (size_t)(kb + bk) * N + bcol * 128 + bc;
            float4 a0 = *(const float4*)gb;
            float4 a1 = *(const float4*)(gb + 4);
            float4 b0 = *(const float4*)(gb + (size_t)16 * N);
            float4 b1 = *(const float4*)(gb + (size_t)16 * N + 4);
            float f0[8] = {a0.x, a0.y, a0.z, a0.w, a1.x, a1.y, a1.z, a1.w};
            float f1[8] = {b0.x, b0.y, b0.z, b0.w, b1.x, b1.y, b1.z, b1.w};
#pragma unroll
            for (int i = 0; i < 8; i++) {
                Bs[bs_off(bc + i, bk)] = f2b(f0[i]);
                Bs[bs_off(bc + i, bk + 16)] = f2b(f1[i]);
            }
        }
        __syncthreads();

        bf16x8 aF[4], bF[4];
#pragma unroll
        for (int m = 0; m < 4; m++)
            aF[m] = *(const bf16x8*)(&As[(wr * 64 + m * 16 + lr) * 40 + lg * 8]);
#pragma unroll
        for (int n = 0; n < 4; n++) {
            int c = wc * 64 + n * 16 + lr;
            bF[n] = *(const bf16x8*)(&Bs[c * 40 + ((lg ^ ((c >> 3) & 3)) << 3)]);
        }
#pragma unroll
        for (int m = 0; m < 4; m++)
#pragma unroll
            for (int n = 0; n < 4; n++)
                acc[m][n] = __builtin_amdgcn_mfma_f32_16x16x32_bf16(aF[m], bF[n], acc[m][n], 0, 0, 0);
        __syncthreads();
    }

#pragma unroll
    for (int m = 0; m < 4; m++)
#pragma unroll
        for (int n = 0; n < 4; n++)
#pragma unroll
            for (int j = 0; j < 4; j++) {
                int row = brow * 128 + wr * 64 + m * 16 + lg * 4 + j;
                int col = bcol * 128 + wc * 64 + n * 16 + lr;
                C[(size_t)row * N + col] = acc[m][n][j];
            }
}

// ---------------- RoPE: f32 strided in -> bf16 packed out ----------------
__global__ __launch_bounds__(256) void rope_kernel(const float* __restrict__ in,
                                                   u16* __restrict__ out, int heads,
                                                   int instride, int incoloff) {
    int idx = blockIdx.x * 256 + threadIdx.x;
    int total = T_SEQ * heads * 32;
    if (idx >= total) return;
    int i = idx & 31;
    int rest = idx >> 5;       // t*heads + h
    int t = rest / heads, hh = rest - t * heads;
    float inv = expf(-(float)i * (9.210340371976184f / 32.0f));
    float ang = (float)t * inv;
    float c = cosf(ang), s = sinf(ang);
    size_t src = (size_t)t * instride + incoloff + hh * HEAD_DIM + 2 * i;
    size_t dst = (size_t)rest * HEAD_DIM + 2 * i;
    float x0 = in[src], x1 = in[src + 1];
    out[dst]     = f2b(x0 * c - x1 * s);
    out[dst + 1] = f2b(x0 * s + x1 * c);
}

// ---------------- flash attention ----------------
__global__ __launch_bounds__(256) void fattn_kernel(const u16* __restrict__ q,
                                                    const u16* __restrict__ k,
                                                    const u16* __restrict__ vt,
                                                    u16* __restrict__ out) {
    __shared__ __align__(16) u16 Ks[KBLK * KSS];
    __shared__ __align__(16) u16 Vt[HEAD_DIM * VTS];
    __shared__ __align__(16) u16 Ps[QBLK * PSS];
    const int tid = threadIdx.x;
    const int qb0 = blockIdx.x * QBLK, h = blockIdx.y, kvh = h >> 2;
    const int w = tid >> 6, lane = tid & 63;
    const int lg = lane >> 4, lr = lane & 15;

    bf16x8 qf0, qf1;
    {
        const u16* src = q + ((size_t)(qb0 + w * 16 + lr) * NH + h) * HEAD_DIM;
        qf0 = *(const bf16x8*)(src + lg * 8);
        qf1 = *(const bf16x8*)(src + 32 + lg * 8);
    }

    f32x4 acc_o[4] = {};
    float m_run[4] = {-1e30f, -1e30f, -1e30f, -1e30f};
    float l_run[4] = {0.f, 0.f, 0.f, 0.f};

    const int ntiles = (qb0 + QBLK - 1) / KBLK + 1;

    for (int kt = 0; kt < ntiles; kt++) {
        const int kb = kt * KBLK;
        __syncthreads();
        for (int c = tid; c < KBLK * 8; c += 256) {
            int row = c >> 3, c8 = (c & 7) << 3;
            *(uint4*)(&Ks[row * KSS + c8]) =
                *(const uint4*)(k + ((size_t)(kb + row) * NKV + kvh) * HEAD_DIM + c8);
        }
        for (int c = tid; c < HEAD_DIM * 16; c += 256) {
            int d = c >> 4, c16 = (c & 15) << 3;
            *(uint4*)(&Vt[d * VTS + c16]) =
                *(const uint4*)(vt + (size_t)(kvh * HEAD_DIM + d) * T_SEQ + kb + c16);
        }
        __syncthreads();

        f32x4 s[8] = {};
#pragma unroll
        for (int n = 0; n < 8; n++) {
            bf16x8 kf0 = *(const bf16x8*)(&Ks[(n * 16 + lr) * KSS + lg * 8]);
            bf16x8 kf1 = *(const bf16x8*)(&Ks[(n * 16 + lr) * KSS + 32 + lg * 8]);
            s[n] = __builtin_amdgcn_mfma_f32_16x16x32_bf16(qf0, kf0, s[n], 0, 0, 0);
            s[n] = __builtin_amdgcn_mfma_f32_16x16x32_bf16(qf1, kf1, s[n], 0, 0, 0);
        }

#pragma unroll
        for (int j = 0; j < 4; j++) {
            int q_g = qb0 + w * 16 + lg * 4 + j;
            float sv[8];
            float tmax = -1e30f;
#pragma unroll
            for (int n = 0; n < 8; n++) {
                float xx = s[n][j] * 0.125f;
                if (kb + n * 16 + lr > q_g) xx = -1e30f;
                sv[n] = xx;
                tmax = fmaxf(tmax, xx);
            }
#pragma unroll
            for (int mm = 1; mm < 16; mm <<= 1) tmax = fmaxf(tmax, __shfl_xor(tmax, mm));
            float mn = fmaxf(m_run[j], tmax);
            float sc = __expf(m_run[j] - mn);
            m_run[j] = mn;
            float rsum = 0.f;
#pragma unroll
            for (int n = 0; n < 8; n++) {
                float p = __expf(sv[n] - mn);
                rsum += p;
                Ps[(w * 16 + lg * 4 + j) * PSS + n * 16 + lr] = f2b(p);
            }
#pragma unroll
            for (int mm = 1; mm < 16; mm <<= 1) rsum += __shfl_xor(rsum, mm);
            l_run[j] = l_run[j] * sc + rsum;
#pragma unroll
            for (int n = 0; n < 4; n++) acc_o[n][j] *= sc;
        }

#pragma unroll
        for (int ks = 0; ks < 4; ks++) {
            bf16x8 pf = *(const bf16x8*)(&Ps[(w * 16 + lr) * PSS + ks * 32 + lg * 8]);
#pragma unroll
            for (int n = 0; n < 4; n++) {
                bf16x8 vf = *(const bf16x8*)(&Vt[(n * 16 + lr) * VTS + ks * 32 + lg * 8]);
                acc_o[n] = __builtin_amdgcn_mfma_f32_16x16x32_bf16(pf, vf, acc_o[n], 0, 0, 0);
            }
        }
    }

#pragma unroll
    for (int n = 0; n < 4; n++)
#pragma unroll
        for (int j = 0; j < 4; j++) {
            int t = qb0 + w * 16 + lg * 4 + j;
            int d = n * 16 + lr;
            out[((size_t)t * NH + h) * HEAD_DIM + d] = f2b(acc_o[n][j] / l_run[j]);
        }
}

// ---------------- silu(gate)*up from packed fGU[t][5632] -> bf16 [t][2816] ----------------
__global__ __launch_bounds__(256) void silu_mul_kernel(const float* __restrict__ gu,
                                                       u16* __restrict__ out) {
    int t = blockIdx.x;
    int c = blockIdx.y * 256 + threadIdx.x;   // < 2816
    float gv = gu[(size_t)t * 5632 + c];
    float uv = gu[(size_t)t * 5632 + 2816 + c];
    float s = gv / (1.f + __expf(-gv));
    out[(size_t)t * FFDIM + c] = f2b(s * uv);
}

// ---------------- residual add ----------------
__global__ __launch_bounds__(256) void add_kernel(float* __restrict__ x,
                                                  const float* __restrict__ y, int n) {
    int i = blockIdx.x * 256 + threadIdx.x;
    if (i < n) x[i] += y[i];
}

// ---------------- host launch ----------------
extern "C" void kernel_launch(void* const* d_in, const int* in_sizes, int n_in,
                              void* d_out, int out_size, void* d_ws, size_t ws_size,
                              hipStream_t stream) {
    const int*   toks = (const int*)d_in[0];
    const float* emb  = (const float*)d_in[1];
    const float* Wq   = (const float*)d_in[2];
    const float* Wk   = (const float*)d_in[3];
    const float* Wv   = (const float*)d_in[4];
    const float* Wo   = (const float*)d_in[5];
    const float* Wg   = (const float*)d_in[6];
    const float* Wu   = (const float*)d_in[7];
    const float* Wd   = (const float*)d_in[8];
    const float* ln1  = (const float*)d_in[9];
    const float* ln2  = (const float*)d_in[10];
    const float* nw   = (const float*)d_in[11];
    const float* Wlm  = (const float*)d_in[12];

    // ---- scratch layout in d_out (262MB, all dead before LM head writes) ----
    char* ob = (char*)d_out;
    const size_t MB = 1024 * 1024;
    float* x    = (float*)(ob + 0 * MB);    // 8MB   residual [T,D]
    float* fqkv = (float*)(ob + 8 * MB);    // 12MB  [T,1536] qkv packed
    float* fGU  = (float*)(ob + 20 * MB);   // 44MB  [T,5632] gate|up packed
    float* fA   = (float*)(ob + 64 * MB);   // 8MB   [T,D] (attn-proj / down out)
    u16* vt     = (u16*)  (ob + 72 * MB);   // 1MB   V^T [256][T]
    u16* qb     = (u16*)  (ob + 74 * MB);   // 4MB
    u16* kb     = (u16*)  (ob + 78 * MB);   // 1MB
    u16* attnb  = (u16*)  (ob + 80 * MB);   // 4MB
    u16* ffb    = (u16*)  (ob + 84 * MB);   // 11.5MB
    size_t woff = 96 * MB;                  // packed bf16 transposed weights (43MB)
    auto walloc = [&](size_t elems) {
        u16* p = (u16*)(ob + woff);
        woff += ((elems * 2 + 255) & ~(size_t)255);
        return p;
    };
    u16 *WqkvT[2], *WoT[2], *WguT[2], *WdT[2];
    for (int l = 0; l < 2; l++) {
        WqkvT[l] = walloc((size_t)1536 * DMODEL);
        WoT[l]   = walloc((size_t)DMODEL * DMODEL);
        WguT[l]  = walloc((size_t)5632 * DMODEL);
        WdT[l]   = walloc((size_t)DMODEL * FFDIM);
    }
    u16* h = (u16*)d_ws;   // 4MB bf16 [T,D]
    bool ws_big = ws_size >= 72 * MB;
    u16* WlmT = ws_big ? (u16*)((char*)d_ws + 4 * MB) : nullptr;  // [NVOCAB][DMODEL]
    (void)in_sizes; (void)n_in; (void)out_size;

    dim3 blk(256);
    auto tcast = [&](const float* in, u16* out, int K, int N) {
        tcast_kernel<<<dim3(N / 32, K / 32), blk, 0, stream>>>(in, out, K, N);
    };
    auto gemm_bt = [&](const u16* A, const u16* BT, float* C, int N, int K) {
        dim3 g(T_SEQ / 128, N / 128);
        gemm_bt_kernel<<<g, blk, 0, stream>>>(A, BT, C, N, K);
    };

    // ---- one-time weight transpose-casts (packed) ----
    for (int l = 0; l < 2; l++) {
        tcast(Wq + (size_t)l * DMODEL * NH * HEAD_DIM,  WqkvT[l],                    DMODEL, NH * HEAD_DIM);
        tcast(Wk + (size_t)l * DMODEL * NKV * HEAD_DIM, WqkvT[l] + (size_t)1024 * DMODEL, DMODEL, NKV * HEAD_DIM);
        tcast(Wv + (size_t)l * DMODEL * NKV * HEAD_DIM, WqkvT[l] + (size_t)1280 * DMODEL, DMODEL, NKV * HEAD_DIM);
        tcast(Wo + (size_t)l * DMODEL * DMODEL,         WoT[l],  DMODEL, DMODEL);
        tcast(Wg + (size_t)l * DMODEL * FFDIM,          WguT[l],                     DMODEL, FFDIM);
        tcast(Wu + (size_t)l * DMODEL * FFDIM,          WguT[l] + (size_t)FFDIM * DMODEL, DMODEL, FFDIM);
        tcast(Wd + (size_t)l * FFDIM * DMODEL,          WdT[l],  FFDIM, DMODEL);
    }
    if (WlmT) tcast(Wlm, WlmT, DMODEL, NVOCAB);

    embed_kernel<<<dim3(T_SEQ * DMODEL / 256), blk, 0, stream>>>(toks, emb, x);

    for (int l = 0; l < 2; l++) {
        // attn block
        rmsnorm_kernel<<<dim3(T_SEQ), blk, 0, stream>>>(x, ln1 + (size_t)l * DMODEL, h);
        gemm_bt(h, WqkvT[l], fqkv, 1536, DMODEL);
        rope_kernel<<<dim3(T_SEQ * NH * 32 / 256), blk, 0, stream>>>(fqkv, qb, NH, 1536, 0);
        rope_kernel<<<dim3(T_SEQ * NKV * 32 / 256), blk, 0, stream>>>(fqkv, kb, NKV, 1536, 1024);
        vtcast_kernel<<<dim3(8, T_SEQ / 32), blk, 0, stream>>>(fqkv, vt);
        fattn_kernel<<<dim3(T_SEQ / QBLK, NH), blk, 0, stream>>>(qb, kb, vt, attnb);
        gemm_bt(attnb, WoT[l], fA, DMODEL, DMODEL);
        add_kernel<<<dim3(T_SEQ * DMODEL / 256), blk, 0, stream>>>(x, fA, T_SEQ * DMODEL);

        // ffn block
        rmsnorm_kernel<<<dim3(T_SEQ), blk, 0, stream>>>(x, ln2 + (size_t)l * DMODEL, h);
        gemm_bt(h, WguT[l], fGU, 5632, DMODEL);
        silu_mul_kernel<<<dim3(T_SEQ, FFDIM / 256), blk, 0, stream>>>(fGU, ffb);
        gemm_bt(ffb, WdT[l], fA, DMODEL, FFDIM);
        add_kernel<<<dim3(T_SEQ * DMODEL / 256), blk, 0, stream>>>(x, fA, T_SEQ * DMODEL);
    }

    // final norm + lm head
    rmsnorm_kernel<<<dim3(T_SEQ), blk, 0, stream>>>(x, nw, h);
    if (WlmT) {
        gemm_bt(h, WlmT, (float*)d_out, NVOCAB, DMODEL);
    } else {
        dim3 g(NVOCAB / 128, T_SEQ / 128);
        gemm_f32b_kernel<<<g, blk, 0, stream>>>(h, Wlm, (float*)d_out, NVOCAB, DMODEL);
    }
}